// Round 8
// baseline (794.199 us; speedup 1.0000x reference)
//
#include <hip/hip_runtime.h>
#include <hip/hip_bf16.h>

#define NN 50000
#define NE 600000
#define D 128

typedef __bf16 bf16x8 __attribute__((ext_vector_type(8)));
typedef __bf16 bf16x4 __attribute__((ext_vector_type(4)));
typedef float f32x4 __attribute__((ext_vector_type(4)));

// ---- helpers -------------------------------------------------------------

// async 16B global->LDS (per-lane global addr, wave-uniform LDS base + lane*16)
static __device__ __forceinline__ void gload_lds16(const void* g, void* l) {
  __builtin_amdgcn_global_load_lds(
      (const __attribute__((address_space(1))) unsigned int*)g,
      (__attribute__((address_space(3))) unsigned int*)l, 16, 0, 0);
}

// Load 8 consecutive f32 along K from a row-major matrix, convert to bf16.
static __device__ __forceinline__ bf16x8 load_a_frag_nc(const float* __restrict__ A,
                                                        int row, int k0) {
  const f32x4* p = (const f32x4*)(A + (size_t)row * D + k0);
  f32x4 v0 = p[0], v1 = p[1];
  bf16x8 r;
  r[0] = (__bf16)v0[0]; r[1] = (__bf16)v0[1]; r[2] = (__bf16)v0[2]; r[3] = (__bf16)v0[3];
  r[4] = (__bf16)v1[0]; r[5] = (__bf16)v1[1]; r[6] = (__bf16)v1[2]; r[7] = (__bf16)v1[3];
  return r;
}

// Stage a 128-row f32 [M][128] tile into XOR-swizzled bf16 LDS (32 KB).
static __device__ __forceinline__ void stage_a_tile128(const float* __restrict__ A, int M,
                                                       int row_base, char* lds, int tid) {
  const int l32 = tid & 31;
  const int g = tid >> 5;
#pragma unroll
  for (int it = 0; it < 16; ++it) {
    int rl = it * 8 + g;
    int r = row_base + rl;
    f32x4 v = {};
    if (r < M) v = *(const f32x4*)(A + (size_t)r * D + l32 * 4);
    bf16x4 b;
    b[0] = (__bf16)v[0]; b[1] = (__bf16)v[1]; b[2] = (__bf16)v[2]; b[3] = (__bf16)v[3];
    int byte = (rl * 256 + l32 * 8) ^ ((rl & 7) << 4);
    *(bf16x4*)(lds + byte) = b;
  }
}

// Read a bf16x8 A-fragment (row rl, k-offset k0) from a swizzled tile.
static __device__ __forceinline__ bf16x8 read_a_frag(const char* lds, int rl, int k0) {
  int byte = (rl * 256 + k0 * 2) ^ ((rl & 7) << 4);
  return *(const bf16x8*)(lds + byte);
}

// DPP add: x + dpp_perm(x). VALU-pipe cross-lane (no LDS latency).
template <int CTRL>
static __device__ __forceinline__ float dpp_add(float x) {
  int v = __builtin_amdgcn_update_dpp(0, __float_as_int(x), CTRL, 0xf, 0xf, true);
  return x + __int_as_float(v);
}

// Sum across each 32-lane half; result in ALL lanes of the half.
static __device__ __forceinline__ float red32(float x) {
  x = dpp_add<0xB1>(x);    // quad xor1
  x = dpp_add<0x4E>(x);    // quad xor2
  x = dpp_add<0x124>(x);   // row_ror:4
  x = dpp_add<0x128>(x);   // row_ror:8
  return x + __shfl_xor(x, 16, 64);
}

// scale * log2(e): exp2(dot * CATT) == exp(dot / sqrt(128))
#define CATT 0.12751744612764933f

// ---- merged prep: 8 weight transposes + segment offsets, one launch ------
struct PrepArgs {
  const float* W[8];
  __bf16* WT[8];
  const int* dst;
  int* offs;
};

__global__ void prep_all(PrepArgs pa) {
  int b = blockIdx.x;
  if (b < 512) {
    int w = b >> 6;
    int t = (b & 63) * 256 + threadIdx.x;  // 16384 per weight
    int n = t & 127, k = t >> 7;
    float v = pa.W[w][k * 128 + n];
    if (w == 0) v *= CATT;  // fold softmax scale into Wq
    pa.WT[w][n * 128 + k] = (__bf16)v;
  } else {
    int n = (b - 512) * 256 + threadIdx.x;
    if (n > NN) return;
    int lo = 0, hi = NE;
    while (lo < hi) {
      int mid = (lo + hi) >> 1;
      if (pa.dst[mid] < n) lo = mid + 1; else hi = mid;
    }
    pa.offs[n] = lo;
  }
}

// ---- batched C[M,128] = A[M,128] @ B_i[128,128] for 5 weights ------------
// mode: 0 = f32 row, 1 = bf16 row,
//       2 = KV interleaved K (elem g*8+slot), 3 = KV interleaved V (+4).
struct GemmBatch {
  const __bf16* BT[5];
  void* C[5];
  const float* bias[5];  // nullptr = none
  int mode[5];
};

__global__ __launch_bounds__(256) void gemm_k128_b(const float* __restrict__ A,
                                                   GemmBatch gb, int M) {
  __shared__ __align__(16) char atile[128 * 256];
  const int y = blockIdx.y;
  const __bf16* __restrict__ BT = gb.BT[y];
  const int tid = threadIdx.x;
  const int lane = tid & 63;
  const int wave = tid >> 6;
  const int wr = wave >> 1, wc = wave & 1;
  const int row0 = blockIdx.x * 128;
  const int col0 = wc * 64;
  const int lr = lane & 15;
  const int lk = (lane >> 4) << 3;

  stage_a_tile128(A, M, row0, atile, tid);
  __syncthreads();

  f32x4 acc[4][4] = {};
#pragma unroll
  for (int kk = 0; kk < 4; ++kk) {
    const int k0 = kk * 32 + lk;
    bf16x8 a[4], b[4];
#pragma unroll
    for (int m = 0; m < 4; ++m) a[m] = read_a_frag(atile, wr * 64 + m * 16 + lr, k0);
#pragma unroll
    for (int n = 0; n < 4; ++n) b[n] = *(const bf16x8*)(BT + (size_t)(col0 + n * 16 + lr) * D + k0);
#pragma unroll
    for (int m = 0; m < 4; ++m)
#pragma unroll
      for (int n = 0; n < 4; ++n)
        acc[m][n] = __builtin_amdgcn_mfma_f32_16x16x32_bf16(a[m], b[n], acc[m][n], 0, 0, 0);
  }
  const int rr = (lane >> 4) * 4;
  float bv[4] = {0.f, 0.f, 0.f, 0.f};
  if (gb.bias[y]) {
#pragma unroll
    for (int n = 0; n < 4; ++n) bv[n] = gb.bias[y][col0 + n * 16 + lr];
  }
  const int mode = gb.mode[y];
#pragma unroll
  for (int m = 0; m < 4; ++m)
#pragma unroll
    for (int j = 0; j < 4; ++j) {
      const int row = row0 + wr * 64 + m * 16 + rr + j;
      if (row < M) {
#pragma unroll
        for (int n = 0; n < 4; ++n) {
          const int c = col0 + n * 16 + lr;
          const float val = acc[m][n][j] + bv[n];
          if (mode == 0) {
            ((float*)gb.C[y])[(size_t)row * D + c] = val;
          } else if (mode == 1) {
            ((__bf16*)gb.C[y])[(size_t)row * D + c] = (__bf16)val;
          } else {
            // interleaved KV row: 32 groups of {k0..3, v0..3}
            const int e = ((c >> 2) << 3) + (c & 3) + (mode == 3 ? 4 : 0);
            ((__bf16*)gb.C[y])[(size_t)row * 256 + e] = (__bf16)val;
          }
        }
      }
    }
}

// ---- attn chunk pipeline macros (static reg indexing only) ---------------
// KV row interleaved: lane l32 loads ONE 16B dwordx4 = {k4|v4} per edge.
#define LD1(P, K, J, SV)                                                     \
  do {                                                                       \
    const int jj_ = (J);                                                     \
    const int jc_ = jj_ < jm ? jj_ : 0;                                      \
    int si_ = __shfl((SV), jj_ & 31, 32);                                    \
    si_ = jj_ < jm ? si_ : 0;                                                \
    kv##P[K] = *(const bf16x8*)(KV + (size_t)si_ * 256 + (l32 << 3));        \
    ee##P[K] = *(const f32x4*)(edge + (size_t)(s0 + jc_) * D + (l32 << 2));  \
  } while (0)

#define LOADC(P, C)                                                          \
  do {                                                                       \
    const int c4_ = (C) * 4;                                                 \
    const int sv_ = (c4_ < 32) ? sidx0 : sidx1;                              \
    LD1(P, 0, c4_ + 0, sv_); LD1(P, 1, c4_ + 1, sv_);                        \
    LD1(P, 2, c4_ + 2, sv_); LD1(P, 3, c4_ + 3, sv_);                        \
  } while (0)

#define CP1(P, K, J)                                                         \
  do {                                                                       \
    const int jj_ = (J);                                                     \
    f32x4 ef_ = ee##P[K];                                                    \
    float x0_ = (float)kv##P[K][0] + ef_[0];                                 \
    float x1_ = (float)kv##P[K][1] + ef_[1];                                 \
    float x2_ = (float)kv##P[K][2] + ef_[2];                                 \
    float x3_ = (float)kv##P[K][3] + ef_[3];                                 \
    float pp_ = fmaf(qs[1], x1_, qs[0] * x0_) + fmaf(qs[3], x3_, qs[2] * x2_); \
    float s_ = red32(pp_);                                                   \
    float w_ = jj_ < jm ? exp2f(s_) : 0.f;                                   \
    l += w_;                                                                 \
    a[0] = fmaf(w_, (float)kv##P[K][4] + ef_[0], a[0]);                      \
    a[1] = fmaf(w_, (float)kv##P[K][5] + ef_[1], a[1]);                      \
    a[2] = fmaf(w_, (float)kv##P[K][6] + ef_[2], a[2]);                      \
    a[3] = fmaf(w_, (float)kv##P[K][7] + ef_[3], a[3]);                      \
  } while (0)

#define COMPC(P, C)                                                          \
  do {                                                                       \
    const int cc4_ = (C) * 4;                                                \
    CP1(P, 0, cc4_ + 0); CP1(P, 1, cc4_ + 1);                                \
    CP1(P, 2, cc4_ + 2); CP1(P, 3, cc4_ + 3);                                \
  } while (0)

// ---- FUSED kernel --------------------------------------------------------
// Roles per group g (3125 groups of 192 edges / 16 nodes):
//   r=0,1: attention block for nodes (g*2+r)*8 .. +7   (uses buf[0:16K))
//   r=2  : EDGE-TRIPLE block: 3 x 64-edge tiles, BARRIER-FREE.
// Edge-triple: each wave owns a 16-row strip per tile end-to-end (its own
// async gathers -> its own MFMA rows -> its own h1 -> its own MFMA2), so the
// only sync is the wave's own vmcnt. No __syncthreads at all.
__global__ __launch_bounds__(256) __attribute__((amdgpu_waves_per_eu(3)))
void fused_edge_attn(
    const float* __restrict__ edge,
    const __bf16* __restrict__ W1bT,
    const __bf16* __restrict__ W2T,
    const __bf16* __restrict__ P1,
    const __bf16* __restrict__ P3,
    const int* __restrict__ dst,
    const int* __restrict__ src,
    const float* __restrict__ b2,
    float* __restrict__ out_fused,
    const float* __restrict__ Q,
    const __bf16* __restrict__ KV,
    const int* __restrict__ offs,
    const __bf16* __restrict__ WoT,
    const float* __restrict__ noderep,
    const float* __restrict__ gamma,
    const float* __restrict__ beta,
    float* __restrict__ out_updated) {
  __shared__ __align__(16) char buf[32768];
  const int tid = threadIdx.x;
  // XCD-affine decode: blockIdx%8 == group%8 for all 3 roles of a group.
  const int b = blockIdx.x;
  const int x = b & 7;
  const int t = b >> 3;          // 0..1172
  const int grp = (t / 3) * 8 + x;
  const int role = t % 3;
  if (grp >= 3125) return;

  if (role == 2) {
    // ============== EDGE-TRIPLE path (192 edges, barrier-free) ===========
    const int wave = tid >> 6;
    const int lane = tid & 63;
    const int lr = lane & 15;
    const int lk = (lane >> 4) << 3;
    const int rr = (lane >> 4) << 2;   // 0,4,8,12
    char* wbuf = buf + wave * 8192;    // [0,4K): P1g then h1 | [4K,8K): P3g
    const int ebase = grp * 192;

    float b2v[8];
#pragma unroll
    for (int n = 0; n < 8; ++n) b2v[n] = b2[n * 16 + lr];

    for (int tt = 0; tt < 3; ++tt) {
      const int er0 = ebase + tt * 64 + wave * 16;  // wave's 16-row strip

      // 1) issue async gathers for this strip (P1[dst], P3[src])
#pragma unroll
      for (int q = 0; q < 4; ++q) {
        const int row = er0 + q * 4 + (lane >> 4);
        const int d = dst[row];
        const int s = src[row];
        gload_lds16((const char*)(P1 + (size_t)d * D) + (lr << 4), wbuf + q * 1024);
        gload_lds16((const char*)(P3 + (size_t)s * D) + (lr << 4), wbuf + 4096 + q * 1024);
      }

      // 2) MFMA1: acc = edge[strip] @ W1b (covers gather latency)
      f32x4 acc[8] = {};
#pragma unroll
      for (int kk = 0; kk < 4; ++kk) {
        const int k0 = kk * 32 + lk;
        bf16x8 a = load_a_frag_nc(edge, er0 + lr, k0);
#pragma unroll
        for (int n = 0; n < 8; ++n) {
          bf16x8 bm = *(const bf16x8*)(W1bT + (size_t)(n * 16 + lr) * D + k0);
          acc[n] = __builtin_amdgcn_mfma_f32_16x16x32_bf16(a, bm, acc[n], 0, 0, 0);
        }
      }

      // 3) wave-local wait: this wave's gathers (and loads/stores) done
      asm volatile("s_waitcnt vmcnt(0)" ::: "memory");

      // 4) fold g = P1g + P3g into acc (linear [16][128] bf16 layout),
      //    then ReLU; reads all issued before any h1 write (same-wave order)
      const __bf16* g1 = (const __bf16*)wbuf;
      const __bf16* g3 = (const __bf16*)(wbuf + 4096);
#pragma unroll
      for (int n = 0; n < 8; ++n)
#pragma unroll
        for (int j = 0; j < 4; ++j) {
          const int rl = rr + j;
          const int c = n * 16 + lr;
          float v = acc[n][j] + (float)g1[rl * 128 + c] + (float)g3[rl * 128 + c];
          acc[n][j] = fmaxf(v, 0.f);
        }

      // 5) h1 -> swizzled bf16 in wbuf[0:4K) (overwrites P1g, reads done)
#pragma unroll
      for (int n = 0; n < 8; ++n)
#pragma unroll
        for (int j = 0; j < 4; ++j) {
          const int rl = rr + j;
          const int c = n * 16 + lr;
          int byte = (rl * 256 + c * 2) ^ ((rl & 7) << 4);
          *(__bf16*)(wbuf + byte) = (__bf16)acc[n][j];
        }

      // 6) MFMA2: fused = h1 @ W2 + b2 (A-frags from own swizzled strip)
      f32x4 acc2[8] = {};
#pragma unroll
      for (int kk = 0; kk < 4; ++kk) {
        const int k0 = kk * 32 + lk;
        bf16x8 a = read_a_frag(wbuf, lr, k0);
#pragma unroll
        for (int n = 0; n < 8; ++n) {
          bf16x8 bm = *(const bf16x8*)(W2T + (size_t)(n * 16 + lr) * D + k0);
          acc2[n] = __builtin_amdgcn_mfma_f32_16x16x32_bf16(a, bm, acc2[n], 0, 0, 0);
        }
      }

      // 7) store
#pragma unroll
      for (int n = 0; n < 8; ++n)
#pragma unroll
        for (int j = 0; j < 4; ++j) {
          const int e = er0 + rr + j;
          const int c = n * 16 + lr;
          out_fused[(size_t)e * D + c] = acc2[n][j] + b2v[n];
        }
    }
  } else {
    // ================= ATTN path (R7 chunk pipeline, unchanged) ==========
    const int nw = tid >> 5;                  // node-slot 0..7 (32-lane halves)
    const int node = (grp * 2 + role) * 8 + nw;  // 6250*8 = 50000
    const int l32 = tid & 31;
    int s0 = offs[node], s1 = offs[node + 1];
    int cnt = s1 - s0;
    // Q pre-scaled by CATT in prep (folded into Wq)
    f32x4 qs = *(const f32x4*)(Q + (size_t)node * D + l32 * 4);
    float l = 0.f;
    f32x4 a = {0.f, 0.f, 0.f, 0.f};

    const int jm = cnt < 64 ? cnt : 64;
    if (jm > 0) {
      int sidx0 = 0, sidx1 = 0;
      if (l32 < cnt) sidx0 = src[s0 + l32];
      if (l32 + 32 < cnt) sidx1 = src[s0 + 32 + l32];
      bf16x8 kv0[4], kv1[4];
      f32x4 ee0[4], ee1[4];
      const int nch = (jm + 3) >> 2;
      LOADC(0, 0);
      for (int c = 0; c < nch; c += 2) {
        if (c + 1 < nch) LOADC(1, c + 1);
        COMPC(0, c);
        if (c + 2 < nch) LOADC(0, c + 2);
        if (c + 1 < nch) COMPC(1, c + 1);
      }
      for (int i = 64; i < cnt; ++i) {
        int si = src[s0 + i];
        bf16x8 kvx = *(const bf16x8*)(KV + (size_t)si * 256 + (l32 << 3));
        f32x4 ef = *(const f32x4*)(edge + (size_t)(s0 + i) * D + (l32 << 2));
        float x0 = (float)kvx[0] + ef[0], x1 = (float)kvx[1] + ef[1];
        float x2 = (float)kvx[2] + ef[2], x3 = (float)kvx[3] + ef[3];
        float pp = fmaf(qs[1], x1, qs[0] * x0) + fmaf(qs[3], x3, qs[2] * x2);
        float w = exp2f(red32(pp));
        l += w;
        a[0] = fmaf(w, (float)kvx[4] + ef[0], a[0]);
        a[1] = fmaf(w, (float)kvx[5] + ef[1], a[1]);
        a[2] = fmaf(w, (float)kvx[6] + ef[2], a[2]);
        a[3] = fmaf(w, (float)kvx[7] + ef[3], a[3]);
      }
    }
    float inv = l > 0.f ? 1.f / l : 0.f;
    f32x4 r;
    r[0] = a[0] * inv; r[1] = a[1] * inv; r[2] = a[2] * inv; r[3] = a[3] * inv;

    // ---- agg row -> swizzled bf16 LDS (row nw of a 16-row A tile) --------
    {
      bf16x4 rb;
      rb[0] = (__bf16)r[0]; rb[1] = (__bf16)r[1];
      rb[2] = (__bf16)r[2]; rb[3] = (__bf16)r[3];
      int byte = (nw * 256 + l32 * 8) ^ ((nw & 7) << 4);
      *(bf16x4*)(buf + byte) = rb;
    }
    __syncthreads();

    // ---- Wo GEMM: rows 0..7 of aggTile @ Wo; cols split 2 n-tiles/wave ---
    {
      const int wave = tid >> 6;
      const int lane = tid & 63;
      const int lr = lane & 15;
      const int lk = (lane >> 4) << 3;
      f32x4 acc[2] = {};
#pragma unroll
      for (int kk = 0; kk < 4; ++kk) {
        int k0 = kk * 32 + lk;
        bf16x8 af = read_a_frag(buf, lr, k0);
#pragma unroll
        for (int tt = 0; tt < 2; ++tt) {
          int nn = wave * 2 + tt;
          bf16x8 bm = *(const bf16x8*)(WoT + (size_t)(nn * 16 + lr) * D + k0);
          acc[tt] = __builtin_amdgcn_mfma_f32_16x16x32_bf16(af, bm, acc[tt], 0, 0, 0);
        }
      }
      float* xl = (float*)(buf + 8192);  // [8][128]
      const int rr = (lane >> 4) * 4;
      if (rr < 8) {
#pragma unroll
        for (int tt = 0; tt < 2; ++tt) {
          int nn = wave * 2 + tt;
#pragma unroll
          for (int j = 0; j < 4; ++j)
            xl[(rr + j) * 128 + nn * 16 + lr] = acc[tt][j];
        }
      }
    }
    __syncthreads();

    // ---- LN per node-slot: updated = LN(node + aggWo) --------------------
    {
      const float* xl = (const float*)(buf + 8192);
      f32x4 xv = *(const f32x4*)(xl + nw * 128 + l32 * 4);
      f32x4 nv = *(const f32x4*)(noderep + (size_t)node * D + l32 * 4);
      float x0 = xv[0] + nv[0], x1 = xv[1] + nv[1];
      float x2 = xv[2] + nv[2], x3 = xv[3] + nv[3];
      float s = red32(x0 + x1 + x2 + x3);
      float mu = s * (1.f / 128.f);
      float d0 = x0 - mu, d1 = x1 - mu, d2 = x2 - mu, d3 = x3 - mu;
      float vv = red32(d0 * d0 + d1 * d1 + d2 * d2 + d3 * d3);
      float rstd = rsqrtf(vv * (1.f / 128.f) + 1e-5f);
      f32x4 g = *(const f32x4*)(gamma + l32 * 4);
      f32x4 bb = *(const f32x4*)(beta + l32 * 4);
      f32x4 o;
      o[0] = d0 * rstd * g[0] + bb[0];
      o[1] = d1 * rstd * g[1] + bb[1];
      o[2] = d2 * rstd * g[2] + bb[2];
      o[3] = d3 * rstd * g[3] + bb[3];
      *(f32x4*)(out_updated + (size_t)node * D + l32 * 4) = o;
    }
  }
}

// ---- launch ---------------------------------------------------------------
extern "C" void kernel_launch(void* const* d_in, const int* in_sizes, int n_in,
                              void* d_out, int out_size, void* d_ws, size_t ws_size,
                              hipStream_t stream) {
  const float* node = (const float*)d_in[0];
  const float* edge = (const float*)d_in[1];
  const int* src = (const int*)d_in[2];
  const int* dst = (const int*)d_in[3];
  const float* Wq = (const float*)d_in[4];
  const float* Wk = (const float*)d_in[5];
  const float* Wv = (const float*)d_in[6];
  const float* Wo = (const float*)d_in[7];
  const float* gamma = (const float*)d_in[8];
  const float* beta = (const float*)d_in[9];
  const float* W1 = (const float*)d_in[10];
  const float* b1 = (const float*)d_in[11];
  const float* W2 = (const float*)d_in[12];
  const float* b2 = (const float*)d_in[13];

  float* out_updated = (float*)d_out;
  float* out_fused = (float*)d_out + (size_t)NN * D;

  char* ws = (char*)d_ws;
  size_t o = 0;
  auto take = [&](size_t bytes) {
    char* p = ws + o;
    o = (o + bytes + 255) & ~(size_t)255;
    return p;
  };
  int* offs = (int*)take((NN + 1) * sizeof(int));
  __bf16* WqT = (__bf16*)take(128 * 128 * 2);
  __bf16* WkT = (__bf16*)take(128 * 128 * 2);
  __bf16* WvT = (__bf16*)take(128 * 128 * 2);
  __bf16* WoT = (__bf16*)take(128 * 128 * 2);
  __bf16* W1aT = (__bf16*)take(128 * 128 * 2);
  __bf16* W1bT = (__bf16*)take(128 * 128 * 2);
  __bf16* W1cT = (__bf16*)take(128 * 128 * 2);
  __bf16* W2T = (__bf16*)take(128 * 128 * 2);
  float* Qb = (float*)take((size_t)NN * D * 4);
  __bf16* KVb = (__bf16*)take((size_t)NN * 256 * 2);  // interleaved {k4|v4} groups
  __bf16* P1b = (__bf16*)take((size_t)NN * D * 2);
  __bf16* P3b = (__bf16*)take((size_t)NN * D * 2);

  PrepArgs pa;
  pa.W[0] = Wq; pa.WT[0] = WqT;
  pa.W[1] = Wk; pa.WT[1] = WkT;
  pa.W[2] = Wv; pa.WT[2] = WvT;
  pa.W[3] = Wo; pa.WT[3] = WoT;
  pa.W[4] = W1; pa.WT[4] = W1aT;
  pa.W[5] = W1 + 128 * 128; pa.WT[5] = W1bT;
  pa.W[6] = W1 + 256 * 128; pa.WT[6] = W1cT;
  pa.W[7] = W2; pa.WT[7] = W2T;
  pa.dst = dst; pa.offs = offs;
  prep_all<<<512 + (NN + 256) / 256, 256, 0, stream>>>(pa);

  int gnode = (NN + 127) / 128;
  GemmBatch gb;
  gb.BT[0] = WqT;  gb.C[0] = Qb;  gb.bias[0] = nullptr; gb.mode[0] = 0;
  gb.BT[1] = WkT;  gb.C[1] = KVb; gb.bias[1] = nullptr; gb.mode[1] = 2;
  gb.BT[2] = WvT;  gb.C[2] = KVb; gb.bias[2] = nullptr; gb.mode[2] = 3;
  gb.BT[3] = W1aT; gb.C[3] = P1b; gb.bias[3] = b1;      gb.mode[3] = 1;
  gb.BT[4] = W1cT; gb.C[4] = P3b; gb.bias[4] = nullptr; gb.mode[4] = 1;
  gemm_k128_b<<<dim3(gnode, 5), 256, 0, stream>>>(node, gb, NN);

  // fused: XCD-affine grid 8 residues x 391 slots x 3 roles (2 attn + 1 edge3)
  fused_edge_attn<<<9384, 256, 0, stream>>>(edge, W1bT, W2T, P1b, P3b, dst, src,
                                            b2, out_fused, Qb, KVb, offs,
                                            WoT, node, gamma, beta, out_updated);
}

// Round 9
// 572.919 us; speedup vs baseline: 1.3862x; 1.3862x over previous
//
#include <hip/hip_runtime.h>
#include <hip/hip_bf16.h>

#define NN 50000
#define NE 600000
#define D 128

typedef __bf16 bf16x8 __attribute__((ext_vector_type(8)));
typedef __bf16 bf16x4 __attribute__((ext_vector_type(4)));
typedef float f32x4 __attribute__((ext_vector_type(4)));

#define MFMA(a, b, c) __builtin_amdgcn_mfma_f32_16x16x32_bf16((a), (b), (c), 0, 0, 0)

// ---- helpers -------------------------------------------------------------

// Load 8 consecutive f32 along K from a row-major matrix, convert to bf16.
static __device__ __forceinline__ bf16x8 load_a_frag_nc(const float* __restrict__ A,
                                                        int row, int k0) {
  const f32x4* p = (const f32x4*)(A + (size_t)row * D + k0);
  f32x4 v0 = p[0], v1 = p[1];
  bf16x8 r;
  r[0] = (__bf16)v0[0]; r[1] = (__bf16)v0[1]; r[2] = (__bf16)v0[2]; r[3] = (__bf16)v0[3];
  r[4] = (__bf16)v1[0]; r[5] = (__bf16)v1[1]; r[6] = (__bf16)v1[2]; r[7] = (__bf16)v1[3];
  return r;
}

// Stage a 128-row f32 [M][128] tile into XOR-swizzled bf16 LDS (32 KB).
static __device__ __forceinline__ void stage_a_tile128(const float* __restrict__ A, int M,
                                                       int row_base, char* lds, int tid) {
  const int l32 = tid & 31;
  const int g = tid >> 5;
#pragma unroll
  for (int it = 0; it < 16; ++it) {
    int rl = it * 8 + g;
    int r = row_base + rl;
    f32x4 v = {};
    if (r < M) v = *(const f32x4*)(A + (size_t)r * D + l32 * 4);
    bf16x4 b;
    b[0] = (__bf16)v[0]; b[1] = (__bf16)v[1]; b[2] = (__bf16)v[2]; b[3] = (__bf16)v[3];
    int byte = (rl * 256 + l32 * 8) ^ ((rl & 7) << 4);
    *(bf16x4*)(lds + byte) = b;
  }
}

// Read a bf16x8 A-fragment (row rl, k-offset k0) from a swizzled 256B-row tile.
static __device__ __forceinline__ bf16x8 read_a_frag(const char* lds, int rl, int k0) {
  int byte = (rl * 256 + k0 * 2) ^ ((rl & 7) << 4);
  return *(const bf16x8*)(lds + byte);
}

// DPP add: x + dpp_perm(x). VALU-pipe cross-lane (no LDS latency).
template <int CTRL>
static __device__ __forceinline__ float dpp_add(float x) {
  int v = __builtin_amdgcn_update_dpp(0, __float_as_int(x), CTRL, 0xf, 0xf, true);
  return x + __int_as_float(v);
}

// Sum within each 16-lane row; result in all lanes of the row.
static __device__ __forceinline__ float red16(float x) {
  x = dpp_add<0xB1>(x);    // quad xor1
  x = dpp_add<0x4E>(x);    // quad xor2
  x = dpp_add<0x124>(x);   // row_ror:4
  x = dpp_add<0x128>(x);   // row_ror:8
  return x;
}

// Sum across each 32-lane half; result in ALL lanes of the half.
static __device__ __forceinline__ float red32(float x) {
  return red16(x) + __shfl_xor(red16(x) * 0.f + x + 0.f, 16, 64) * 0.f +
         __shfl_xor(red16(x), 16, 64);
}

// scale * log2(e): exp2(dot * CATT) == exp(dot / sqrt(128))
#define CATT 0.12751744612764933f

// ---- merged prep: 8 weight transposes + segment offsets, one launch ------
struct PrepArgs {
  const float* W[8];
  __bf16* WT[8];
  const int* dst;
  int* offs;
};

__global__ void prep_all(PrepArgs pa) {
  int b = blockIdx.x;
  if (b < 512) {
    int w = b >> 6;
    int t = (b & 63) * 256 + threadIdx.x;  // 16384 per weight
    int n = t & 127, k = t >> 7;
    float v = pa.W[w][k * 128 + n];
    if (w == 0) v *= CATT;  // fold softmax scale into Wq
    pa.WT[w][n * 128 + k] = (__bf16)v;
  } else {
    int n = (b - 512) * 256 + threadIdx.x;
    if (n > NN) return;
    int lo = 0, hi = NE;
    while (lo < hi) {
      int mid = (lo + hi) >> 1;
      if (pa.dst[mid] < n) lo = mid + 1; else hi = mid;
    }
    pa.offs[n] = lo;
  }
}

// ---- batched C[M,128] = A[M,128] @ B_i[128,128] for 5 weights ------------
// mode: 1 = bf16 row, 2 = KV row K-half, 3 = KV row V-half,
//       4 = Q hi/lo bf16 split row ([row][256]: qh | ql).
struct GemmBatch {
  const __bf16* BT[5];
  void* C[5];
  const float* bias[5];  // nullptr = none
  int mode[5];
};

__global__ __launch_bounds__(256) void gemm_k128_b(const float* __restrict__ A,
                                                   GemmBatch gb, int M) {
  __shared__ __align__(16) char atile[128 * 256];
  const int y = blockIdx.y;
  const __bf16* __restrict__ BT = gb.BT[y];
  const int tid = threadIdx.x;
  const int lane = tid & 63;
  const int wave = tid >> 6;
  const int wr = wave >> 1, wc = wave & 1;
  const int row0 = blockIdx.x * 128;
  const int col0 = wc * 64;
  const int lr = lane & 15;
  const int lk = (lane >> 4) << 3;

  stage_a_tile128(A, M, row0, atile, tid);
  __syncthreads();

  f32x4 acc[4][4] = {};
#pragma unroll
  for (int kk = 0; kk < 4; ++kk) {
    const int k0 = kk * 32 + lk;
    bf16x8 a[4], b[4];
#pragma unroll
    for (int m = 0; m < 4; ++m) a[m] = read_a_frag(atile, wr * 64 + m * 16 + lr, k0);
#pragma unroll
    for (int n = 0; n < 4; ++n) b[n] = *(const bf16x8*)(BT + (size_t)(col0 + n * 16 + lr) * D + k0);
#pragma unroll
    for (int m = 0; m < 4; ++m)
#pragma unroll
      for (int n = 0; n < 4; ++n)
        acc[m][n] = MFMA(a[m], b[n], acc[m][n]);
  }
  const int rr = (lane >> 4) * 4;
  float bv[4] = {0.f, 0.f, 0.f, 0.f};
  if (gb.bias[y]) {
#pragma unroll
    for (int n = 0; n < 4; ++n) bv[n] = gb.bias[y][col0 + n * 16 + lr];
  }
  const int mode = gb.mode[y];
#pragma unroll
  for (int m = 0; m < 4; ++m)
#pragma unroll
    for (int j = 0; j < 4; ++j) {
      const int row = row0 + wr * 64 + m * 16 + rr + j;
      if (row < M) {
#pragma unroll
        for (int n = 0; n < 4; ++n) {
          const int c = col0 + n * 16 + lr;
          const float val = acc[m][n][j] + bv[n];
          __bf16* C = (__bf16*)gb.C[y];
          if (mode == 1) {
            C[(size_t)row * D + c] = (__bf16)val;
          } else if (mode == 2) {
            C[(size_t)row * 256 + c] = (__bf16)val;           // K half
          } else if (mode == 3) {
            C[(size_t)row * 256 + 128 + c] = (__bf16)val;     // V half
          } else {
            __bf16 vh = (__bf16)val;
            __bf16 vl = (__bf16)(val - (float)vh);
            C[(size_t)row * 256 + c] = vh;                    // Q hi
            C[(size_t)row * 256 + 128 + c] = vl;              // Q lo
          }
        }
      }
    }
}

// ---- FUSED: MFMA-attention blocks (16 nodes) + 64-edge MLP blocks --------
// LDS (34880 B): KE[64][256B swz] | VET2[64][256B col-pair swz] | PT[16][128B swz] | l[16]
__global__ __launch_bounds__(256) __attribute__((amdgpu_waves_per_eu(3)))
void fused_edge_attn(
    const float* __restrict__ edge,
    const __bf16* __restrict__ W1bT,
    const __bf16* __restrict__ W2T,
    const __bf16* __restrict__ P1,
    const __bf16* __restrict__ P3,
    const int* __restrict__ dst,
    const int* __restrict__ src,
    const float* __restrict__ b2,
    float* __restrict__ out_fused,
    const __bf16* __restrict__ Qsp,
    const __bf16* __restrict__ KV,
    const int* __restrict__ offs,
    const __bf16* __restrict__ WoT,
    const float* __restrict__ noderep,
    const float* __restrict__ gamma,
    const float* __restrict__ beta,
    float* __restrict__ out_updated) {
  __shared__ __align__(16) char lds[34880];
  const int tid = threadIdx.x;
  // XCD-affine decode: blockIdx%8 == group%8 for all 4 roles of a group.
  const int b = blockIdx.x;
  const int x = b & 7;
  const int t = b >> 3;           // 0..1563
  const int grp = (t >> 2) * 8 + x;
  const int role = t & 3;         // 0 = attn(16 nodes), 1..3 = edge(64)
  if (grp >= 3125) return;

  const int wave = tid >> 6;
  const int lane = tid & 63;
  const int lr = lane & 15;
  const int kg = lane >> 4;       // k-group 0..3
  const int rr = kg << 2;         // C-layout row base
  const int lk = kg << 3;

  if (role != 0) {
    // ================= EDGE path (R5: 64-edge, reg-gather, 1 barrier) ====
    const int ebi = grp * 3 + (role - 1);  // 0..9374
    const int eb = ebi * 64;
    const int wr = wave >> 1, wc = wave & 1;
    const int col0 = wc * 64;

    f32x4 acc[2][4] = {};
#pragma unroll
    for (int kk = 0; kk < 4; ++kk) {
      const int k0 = kk * 32 + lk;
      bf16x8 a[2], bm[4];
#pragma unroll
      for (int m = 0; m < 2; ++m) a[m] = load_a_frag_nc(edge, eb + wr * 32 + m * 16 + lr, k0);
#pragma unroll
      for (int n = 0; n < 4; ++n) bm[n] = *(const bf16x8*)(W1bT + (size_t)(col0 + n * 16 + lr) * D + k0);
#pragma unroll
      for (int m = 0; m < 2; ++m)
#pragma unroll
        for (int n = 0; n < 4; ++n)
          acc[m][n] = MFMA(a[m], bm[n], acc[m][n]);
    }

    // epilogue: h1 = relu(acc + P1[dst] + P3[src]) -> lds (swizzled bf16)
#pragma unroll
    for (int m = 0; m < 2; ++m) {
#pragma unroll
      for (int j = 0; j < 4; ++j) {
        const int rl = wr * 32 + m * 16 + rr + j;
        const __bf16* __restrict__ p1r = P1 + (size_t)dst[eb + rl] * D;
        const __bf16* __restrict__ p3r = P3 + (size_t)src[eb + rl] * D;
#pragma unroll
        for (int n = 0; n < 4; ++n) {
          const int c = col0 + n * 16 + lr;
          float v = fmaxf(acc[m][n][j] + (float)p1r[c] + (float)p3r[c], 0.f);
          int byte = (rl * 256 + c * 2) ^ ((rl & 7) << 4);
          *(__bf16*)(lds + byte) = (__bf16)v;
        }
      }
    }
    __syncthreads();

    // MFMA2: fused = h1 @ W2 + b2
    float b2v[4];
#pragma unroll
    for (int n = 0; n < 4; ++n) b2v[n] = b2[col0 + n * 16 + lr];
    f32x4 acc2[2][4] = {};
#pragma unroll
    for (int kk = 0; kk < 4; ++kk) {
      const int k0 = kk * 32 + lk;
      bf16x8 a[2], bm[4];
#pragma unroll
      for (int m = 0; m < 2; ++m) a[m] = read_a_frag(lds, wr * 32 + m * 16 + lr, k0);
#pragma unroll
      for (int n = 0; n < 4; ++n) bm[n] = *(const bf16x8*)(W2T + (size_t)(col0 + n * 16 + lr) * D + k0);
#pragma unroll
      for (int m = 0; m < 2; ++m)
#pragma unroll
        for (int n = 0; n < 4; ++n)
          acc2[m][n] = MFMA(a[m], bm[n], acc2[m][n]);
    }
#pragma unroll
    for (int m = 0; m < 2; ++m)
#pragma unroll
      for (int j = 0; j < 4; ++j) {
        int rl = wr * 32 + m * 16 + rr + j;
        int e = eb + rl;
#pragma unroll
        for (int n = 0; n < 4; ++n) {
          int c = col0 + n * 16 + lr;
          out_fused[(size_t)e * D + c] = acc2[m][n][j] + b2v[n];
        }
      }
  } else {
    // ================= MFMA ATTENTION (16 nodes, tiles of 64 edges) ======
    char* KE = lds;                       // [64 edges][256B] swizzled bf16 (K+E)
    char* VET = lds + 16384;              // VE^T col-pair: byte(col,e) below
    char* PT = lds + 32768;               // P^T [16 nodes][128B] swizzled bf16
    float* l_lds = (float*)(lds + 34816); // 16 floats
    const int n0 = grp * 16;

    if (tid < 16) l_lds[tid] = 0.f;

    const int e0 = offs[n0], e1 = offs[n0 + 16];
    const int L = e1 - e0;
    const int T = (L + 63) >> 6;

    f32x4 accp[2] = {};                          // PV accumulator (persist)
    float lsum0 = 0.f, lsum1 = 0.f, lsum2 = 0.f, lsum3 = 0.f;

    const int se = tid >> 2;      // staging: edge row 0..63
    const int sq = tid & 3;       // col quarter
    const int c0 = sq << 5;
    const int el = (wave << 4) + lr;  // this lane's edge col in QK C-layout

    for (int tt = 0; tt < T; ++tt) {
      const int et = e0 + (tt << 6);
      // ---- stage KE + VET (cooperative, all vector global loads) --------
      {
        int eg = et + se;
        int ec = eg < e1 ? eg : e1 - 1;  // clamp; garbage rows masked via PT=0
        int si = src[ec];
        const float* ep = edge + (size_t)ec * D + c0;
        const __bf16* kp = KV + (size_t)si * 256 + c0;
        f32x4 e4[8];
#pragma unroll
        for (int i = 0; i < 8; ++i) e4[i] = *(const f32x4*)(ep + i * 4);
        bf16x8 k8[4], v8[4];
#pragma unroll
        for (int i = 0; i < 4; ++i) {
          k8[i] = *(const bf16x8*)(kp + i * 8);
          v8[i] = *(const bf16x8*)(kp + 128 + i * 8);
        }
#pragma unroll
        for (int i = 0; i < 4; ++i) {
          bf16x8 o;
#pragma unroll
          for (int u = 0; u < 8; ++u)
            o[u] = (__bf16)((float)k8[i][u] + e4[i * 2 + (u >> 2)][u & 3]);
          int byte = (se * 256 + ((c0 + i * 8) << 1)) ^ ((se & 7) << 4);
          *(bf16x8*)(KE + byte) = o;
        }
#pragma unroll
        for (int i = 0; i < 32; ++i) {
          int col = c0 + i;
          float v = (float)v8[i >> 3][i & 7] + e4[i >> 2][i & 3];
          int byte = ((col >> 1) * 256 + (col & 1) * 128 + (se << 1)) ^
                     ((((col >> 1) ^ (col >> 5)) & 7) << 4);
          *(__bf16*)(VET + byte) = (__bf16)v;
        }
      }
      __syncthreads();

      // ---- QK: S^T[node][edge] = Q @ KE^T (Q hi/lo split) ---------------
      f32x4 accs = {};
      {
        const __bf16* Qs = Qsp + (size_t)(n0 + lr) * 256;
#pragma unroll
        for (int kk = 0; kk < 4; ++kk) {
          int k0 = kk * 32 + lk;
          bf16x8 qh = *(const bf16x8*)(Qs + k0);
          bf16x8 ql = *(const bf16x8*)(Qs + 128 + k0);
          bf16x8 ke = read_a_frag(KE, el, k0);  // wave's 16-edge n-tile
          accs = MFMA(qh, ke, accs);
          accs = MFMA(ql, ke, accs);
        }
      }
      // ---- P build: mask by dst, exp2, store P^T ------------------------
      {
        int eg = et + el;
        int de = (eg < e1) ? (dst[eg] - n0) : -1;
#pragma unroll
        for (int j = 0; j < 4; ++j) {
          float w = (rr + j == de) ? exp2f(accs[j]) : 0.f;
          __bf16 wb = (__bf16)w;
          float wf = (float)wb;
          if (j == 0) lsum0 += wf; else if (j == 1) lsum1 += wf;
          else if (j == 2) lsum2 += wf; else lsum3 += wf;
          int byte = (((rr + j) << 7) + (el << 1)) ^ (((rr + j) & 7) << 4);
          *(__bf16*)(PT + byte) = wb;
        }
      }
      __syncthreads();

      // ---- PV: agg += P^T @ VE (K = 64 edges) ---------------------------
#pragma unroll
      for (int kk = 0; kk < 2; ++kk) {
        int k = kk * 32 + lk;
        int abyte = ((lr << 7) + (k << 1)) ^ ((lr & 7) << 4);
        bf16x8 ap = *(const bf16x8*)(PT + abyte);
#pragma unroll
        for (int nt = 0; nt < 2; ++nt) {
          int col = (wave << 5) + (nt << 4) + lr;
          int bbyte = ((col >> 1) * 256 + (col & 1) * 128 + (k << 1)) ^
                      ((((col >> 1) ^ (col >> 5)) & 7) << 4);
          bf16x8 bv = *(const bf16x8*)(VET + bbyte);
          accp[nt] = MFMA(ap, bv, accp[nt]);
        }
      }
      __syncthreads();
    }

    // ---- l: reduce 16-lane rows, cross-wave via LDS atomics -------------
    {
      float r0 = red16(lsum0), r1 = red16(lsum1);
      float r2 = red16(lsum2), r3 = red16(lsum3);
      if ((lane & 15) == 0) {
        atomicAdd(l_lds + rr + 0, r0);
        atomicAdd(l_lds + rr + 1, r1);
        atomicAdd(l_lds + rr + 2, r2);
        atomicAdd(l_lds + rr + 3, r3);
      }
    }
    __syncthreads();

    // ---- normalize, agg -> KE region as 16-row swizzled A-tile ----------
    {
#pragma unroll
      for (int nt = 0; nt < 2; ++nt) {
        int col = (wave << 5) + (nt << 4) + lr;
#pragma unroll
        for (int j = 0; j < 4; ++j) {
          int node = rr + j;
          float lv = l_lds[node];
          float inv = lv > 0.f ? 1.f / lv : 0.f;
          int byte = (node * 256 + (col << 1)) ^ ((node & 7) << 4);
          *(__bf16*)(KE + byte) = (__bf16)(accp[nt][j] * inv);
        }
      }
    }
    __syncthreads();

    // ---- Wo GEMM: xl[16][128] = agg @ Wo --------------------------------
    {
      f32x4 aw[2] = {};
#pragma unroll
      for (int kk = 0; kk < 4; ++kk) {
        int k0 = kk * 32 + lk;
        bf16x8 af = read_a_frag(KE, lr, k0);
#pragma unroll
        for (int nt = 0; nt < 2; ++nt) {
          int nn = (wave << 1) + nt;
          bf16x8 bm = *(const bf16x8*)(WoT + (size_t)(nn * 16 + lr) * D + k0);
          aw[nt] = MFMA(af, bm, aw[nt]);
        }
      }
      float* xl = (float*)VET;  // [16][128] f32 (VET dead)
#pragma unroll
      for (int nt = 0; nt < 2; ++nt) {
        int nn = (wave << 1) + nt;
#pragma unroll
        for (int j = 0; j < 4; ++j)
          xl[(rr + j) * 128 + nn * 16 + lr] = aw[nt][j];
      }
    }
    __syncthreads();

    // ---- LN: half-wave h -> nodes 2h, 2h+1 ------------------------------
    {
      const int h = tid >> 5;
      const int l32 = tid & 31;
      const float* xl = (const float*)VET;
      f32x4 g = *(const f32x4*)(gamma + l32 * 4);
      f32x4 bb = *(const f32x4*)(beta + l32 * 4);
#pragma unroll
      for (int which = 0; which < 2; ++which) {
        int nl = h * 2 + which;
        int node = n0 + nl;
        f32x4 xv = *(const f32x4*)(xl + nl * 128 + l32 * 4);
        f32x4 nv = *(const f32x4*)(noderep + (size_t)node * D + l32 * 4);
        float x0 = xv[0] + nv[0], x1 = xv[1] + nv[1];
        float x2 = xv[2] + nv[2], x3 = xv[3] + nv[3];
        float s = red16(x0 + x1 + x2 + x3);
        s += __shfl_xor(s, 16, 64);
        float mu = s * (1.f / 128.f);
        float d0 = x0 - mu, d1 = x1 - mu, d2 = x2 - mu, d3 = x3 - mu;
        float vv = red16(d0 * d0 + d1 * d1 + d2 * d2 + d3 * d3);
        vv += __shfl_xor(vv, 16, 64);
        float rstd = rsqrtf(vv * (1.f / 128.f) + 1e-5f);
        f32x4 o;
        o[0] = d0 * rstd * g[0] + bb[0];
        o[1] = d1 * rstd * g[1] + bb[1];
        o[2] = d2 * rstd * g[2] + bb[2];
        o[3] = d3 * rstd * g[3] + bb[3];
        *(f32x4*)(out_updated + (size_t)node * D + l32 * 4) = o;
      }
    }
  }
}

// ---- launch ---------------------------------------------------------------
extern "C" void kernel_launch(void* const* d_in, const int* in_sizes, int n_in,
                              void* d_out, int out_size, void* d_ws, size_t ws_size,
                              hipStream_t stream) {
  const float* node = (const float*)d_in[0];
  const float* edge = (const float*)d_in[1];
  const int* src = (const int*)d_in[2];
  const int* dst = (const int*)d_in[3];
  const float* Wq = (const float*)d_in[4];
  const float* Wk = (const float*)d_in[5];
  const float* Wv = (const float*)d_in[6];
  const float* Wo = (const float*)d_in[7];
  const float* gamma = (const float*)d_in[8];
  const float* beta = (const float*)d_in[9];
  const float* W1 = (const float*)d_in[10];
  const float* b1 = (const float*)d_in[11];
  const float* W2 = (const float*)d_in[12];
  const float* b2 = (const float*)d_in[13];

  float* out_updated = (float*)d_out;
  float* out_fused = (float*)d_out + (size_t)NN * D;

  char* ws = (char*)d_ws;
  size_t o = 0;
  auto take = [&](size_t bytes) {
    char* p = ws + o;
    o = (o + bytes + 255) & ~(size_t)255;
    return p;
  };
  int* offs = (int*)take((NN + 1) * sizeof(int));
  __bf16* WqT = (__bf16*)take(128 * 128 * 2);
  __bf16* WkT = (__bf16*)take(128 * 128 * 2);
  __bf16* WvT = (__bf16*)take(128 * 128 * 2);
  __bf16* WoT = (__bf16*)take(128 * 128 * 2);
  __bf16* W1aT = (__bf16*)take(128 * 128 * 2);
  __bf16* W1bT = (__bf16*)take(128 * 128 * 2);
  __bf16* W1cT = (__bf16*)take(128 * 128 * 2);
  __bf16* W2T = (__bf16*)take(128 * 128 * 2);
  __bf16* Qsp = (__bf16*)take((size_t)NN * 256 * 2);  // [qh(128) | ql(128)]
  __bf16* KVb = (__bf16*)take((size_t)NN * 256 * 2);  // [K(128) | V(128)]
  __bf16* P1b = (__bf16*)take((size_t)NN * D * 2);
  __bf16* P3b = (__bf16*)take((size_t)NN * D * 2);

  PrepArgs pa;
  pa.W[0] = Wq; pa.WT[0] = WqT;
  pa.W[1] = Wk; pa.WT[1] = WkT;
  pa.W[2] = Wv; pa.WT[2] = WvT;
  pa.W[3] = Wo; pa.WT[3] = WoT;
  pa.W[4] = W1; pa.WT[4] = W1aT;
  pa.W[5] = W1 + 128 * 128; pa.WT[5] = W1bT;
  pa.W[6] = W1 + 256 * 128; pa.WT[6] = W1cT;
  pa.W[7] = W2; pa.WT[7] = W2T;
  pa.dst = dst; pa.offs = offs;
  prep_all<<<512 + (NN + 256) / 256, 256, 0, stream>>>(pa);

  int gnode = (NN + 127) / 128;
  GemmBatch gb;
  gb.BT[0] = WqT;  gb.C[0] = Qsp; gb.bias[0] = nullptr; gb.mode[0] = 4;
  gb.BT[1] = WkT;  gb.C[1] = KVb; gb.bias[1] = nullptr; gb.mode[1] = 2;
  gb.BT[2] = WvT;  gb.C[2] = KVb; gb.bias[2] = nullptr; gb.mode[2] = 3;
  gb.BT[3] = W1aT; gb.C[3] = P1b; gb.bias[3] = b1;      gb.mode[3] = 1;
  gb.BT[4] = W1cT; gb.C[4] = P3b; gb.bias[4] = nullptr; gb.mode[4] = 1;
  gemm_k128_b<<<dim3(gnode, 5), 256, 0, stream>>>(node, gb, NN);

  // fused: XCD-affine grid 8 residues x 391 slots x 4 roles (1 attn + 3 edge)
  fused_edge_attn<<<12512, 256, 0, stream>>>(edge, W1bT, W2T, P1b, P3b, dst, src,
                                             b2, out_fused, Qsp, KVb, offs,
                                             WoT, node, gamma, beta, out_updated);
}

// Round 10
// 471.055 us; speedup vs baseline: 1.6860x; 1.2162x over previous
//
#include <hip/hip_runtime.h>
#include <hip/hip_bf16.h>

#define NN 50000
#define NE 600000
#define D 128

typedef __bf16 bf16x8 __attribute__((ext_vector_type(8)));
typedef __bf16 bf16x4 __attribute__((ext_vector_type(4)));
typedef float f32x4 __attribute__((ext_vector_type(4)));

#define MFMA(a, b, c) __builtin_amdgcn_mfma_f32_16x16x32_bf16((a), (b), (c), 0, 0, 0)

// ---- helpers -------------------------------------------------------------

// Load 8 consecutive f32 along K from a row-major matrix, convert to bf16.
static __device__ __forceinline__ bf16x8 load_a_frag_nc(const float* __restrict__ A,
                                                        int row, int k0) {
  const f32x4* p = (const f32x4*)(A + (size_t)row * D + k0);
  f32x4 v0 = p[0], v1 = p[1];
  bf16x8 r;
  r[0] = (__bf16)v0[0]; r[1] = (__bf16)v0[1]; r[2] = (__bf16)v0[2]; r[3] = (__bf16)v0[3];
  r[4] = (__bf16)v1[0]; r[5] = (__bf16)v1[1]; r[6] = (__bf16)v1[2]; r[7] = (__bf16)v1[3];
  return r;
}

// Stage a 128-row f32 [M][128] tile into XOR-swizzled bf16 LDS (32 KB).
static __device__ __forceinline__ void stage_a_tile128(const float* __restrict__ A, int M,
                                                       int row_base, char* lds, int tid) {
  const int l32 = tid & 31;
  const int g = tid >> 5;
#pragma unroll
  for (int it = 0; it < 16; ++it) {
    int rl = it * 8 + g;
    int r = row_base + rl;
    f32x4 v = {};
    if (r < M) v = *(const f32x4*)(A + (size_t)r * D + l32 * 4);
    bf16x4 b;
    b[0] = (__bf16)v[0]; b[1] = (__bf16)v[1]; b[2] = (__bf16)v[2]; b[3] = (__bf16)v[3];
    int byte = (rl * 256 + l32 * 8) ^ ((rl & 7) << 4);
    *(bf16x4*)(lds + byte) = b;
  }
}

// Read a bf16x8 A-fragment (row rl, k-offset k0) from a swizzled tile.
static __device__ __forceinline__ bf16x8 read_a_frag(const char* lds, int rl, int k0) {
  int byte = (rl * 256 + k0 * 2) ^ ((rl & 7) << 4);
  return *(const bf16x8*)(lds + byte);
}

// DPP add: x + dpp_perm(x). VALU-pipe cross-lane (no LDS latency).
template <int CTRL>
static __device__ __forceinline__ float dpp_add(float x) {
  int v = __builtin_amdgcn_update_dpp(0, __float_as_int(x), CTRL, 0xf, 0xf, true);
  return x + __int_as_float(v);
}

// Sum across each 32-lane half; result in ALL lanes of the half.
static __device__ __forceinline__ float red32(float x) {
  x = dpp_add<0xB1>(x);    // quad xor1
  x = dpp_add<0x4E>(x);    // quad xor2
  x = dpp_add<0x124>(x);   // row_ror:4
  x = dpp_add<0x128>(x);   // row_ror:8
  return x + __shfl_xor(x, 16, 64);
}

// scale * log2(e): exp2(dot * CATT) == exp(dot / sqrt(128))
#define CATT 0.12751744612764933f

// ---- merged prep: 8 weight transposes + segment offsets, one launch ------
struct PrepArgs {
  const float* W[8];
  __bf16* WT[8];
  const int* dst;
  int* offs;
};

__global__ void prep_all(PrepArgs pa) {
  int b = blockIdx.x;
  if (b < 512) {
    int w = b >> 6;
    int t = (b & 63) * 256 + threadIdx.x;  // 16384 per weight
    int n = t & 127, k = t >> 7;
    float v = pa.W[w][k * 128 + n];
    if (w == 0) v *= CATT;  // fold softmax scale into Wq
    pa.WT[w][n * 128 + k] = (__bf16)v;
  } else {
    int n = (b - 512) * 256 + threadIdx.x;
    if (n > NN) return;
    int lo = 0, hi = NE;
    while (lo < hi) {
      int mid = (lo + hi) >> 1;
      if (pa.dst[mid] < n) lo = mid + 1; else hi = mid;
    }
    pa.offs[n] = lo;
  }
}

// ---- batched C[M,128] = A[M,128] @ B_i[128,128] for 5 weights ------------
// mode: 0 = f32 row, 1 = bf16 row,
//       2 = KV interleaved K (elem g*8+slot), 3 = KV interleaved V (+4).
struct GemmBatch {
  const __bf16* BT[5];
  void* C[5];
  const float* bias[5];  // nullptr = none
  int mode[5];
};

__global__ __launch_bounds__(256) void gemm_k128_b(const float* __restrict__ A,
                                                   GemmBatch gb, int M) {
  __shared__ __align__(16) char atile[128 * 256];
  const int y = blockIdx.y;
  const __bf16* __restrict__ BT = gb.BT[y];
  const int tid = threadIdx.x;
  const int lane = tid & 63;
  const int wave = tid >> 6;
  const int wr = wave >> 1, wc = wave & 1;
  const int row0 = blockIdx.x * 128;
  const int col0 = wc * 64;
  const int lr = lane & 15;
  const int lk = (lane >> 4) << 3;

  stage_a_tile128(A, M, row0, atile, tid);
  __syncthreads();

  f32x4 acc[4][4] = {};
#pragma unroll
  for (int kk = 0; kk < 4; ++kk) {
    const int k0 = kk * 32 + lk;
    bf16x8 a[4], b[4];
#pragma unroll
    for (int m = 0; m < 4; ++m) a[m] = read_a_frag(atile, wr * 64 + m * 16 + lr, k0);
#pragma unroll
    for (int n = 0; n < 4; ++n) b[n] = *(const bf16x8*)(BT + (size_t)(col0 + n * 16 + lr) * D + k0);
#pragma unroll
    for (int m = 0; m < 4; ++m)
#pragma unroll
      for (int n = 0; n < 4; ++n)
        acc[m][n] = MFMA(a[m], b[n], acc[m][n]);
  }
  const int rr = (lane >> 4) * 4;
  float bv[4] = {0.f, 0.f, 0.f, 0.f};
  if (gb.bias[y]) {
#pragma unroll
    for (int n = 0; n < 4; ++n) bv[n] = gb.bias[y][col0 + n * 16 + lr];
  }
  const int mode = gb.mode[y];
#pragma unroll
  for (int m = 0; m < 4; ++m)
#pragma unroll
    for (int j = 0; j < 4; ++j) {
      const int row = row0 + wr * 64 + m * 16 + rr + j;
      if (row < M) {
#pragma unroll
        for (int n = 0; n < 4; ++n) {
          const int c = col0 + n * 16 + lr;
          const float val = acc[m][n][j] + bv[n];
          if (mode == 0) {
            ((float*)gb.C[y])[(size_t)row * D + c] = val;
          } else if (mode == 1) {
            ((__bf16*)gb.C[y])[(size_t)row * D + c] = (__bf16)val;
          } else {
            // interleaved KV row: 32 groups of {k0..3, v0..3}
            const int e = ((c >> 2) << 3) + (c & 3) + (mode == 3 ? 4 : 0);
            ((__bf16*)gb.C[y])[(size_t)row * 256 + e] = (__bf16)val;
          }
        }
      }
    }
}

// ---- EDGE MLP kernel (R5 path standalone; 64-edge blocks, 16 KB LDS) -----
__global__ __launch_bounds__(256) void edge_mlp(
    const float* __restrict__ edge,
    const __bf16* __restrict__ W1bT,
    const __bf16* __restrict__ W2T,
    const __bf16* __restrict__ P1,
    const __bf16* __restrict__ P3,
    const int* __restrict__ dst,
    const int* __restrict__ src,
    const float* __restrict__ b2,
    float* __restrict__ out_fused) {
  __shared__ __align__(16) char buf[64 * 256];  // 16 KB
  const int tid = threadIdx.x;
  const int eb = blockIdx.x * 64;
  const int lane = tid & 63;
  const int wave = tid >> 6;
  const int wr = wave >> 1, wc = wave & 1;
  const int lr = lane & 15;
  const int lk = (lane >> 4) << 3;
  const int col0 = wc * 64;
  const int rr = (lane >> 4) * 4;

  // MFMA1: acc = edge @ W1b (A-frags direct from global)
  f32x4 acc[2][4] = {};
#pragma unroll
  for (int kk = 0; kk < 4; ++kk) {
    const int k0 = kk * 32 + lk;
    bf16x8 a[2], bm[4];
#pragma unroll
    for (int m = 0; m < 2; ++m) a[m] = load_a_frag_nc(edge, eb + wr * 32 + m * 16 + lr, k0);
#pragma unroll
    for (int n = 0; n < 4; ++n) bm[n] = *(const bf16x8*)(W1bT + (size_t)(col0 + n * 16 + lr) * D + k0);
#pragma unroll
    for (int m = 0; m < 2; ++m)
#pragma unroll
      for (int n = 0; n < 4; ++n)
        acc[m][n] = MFMA(a[m], bm[n], acc[m][n]);
  }

  // epilogue: h1 = relu(acc + P1[dst] + P3[src]) -> buf (swizzled bf16)
#pragma unroll
  for (int m = 0; m < 2; ++m) {
#pragma unroll
    for (int j = 0; j < 4; ++j) {
      const int rl = wr * 32 + m * 16 + rr + j;
      const __bf16* __restrict__ p1r = P1 + (size_t)dst[eb + rl] * D;
      const __bf16* __restrict__ p3r = P3 + (size_t)src[eb + rl] * D;
#pragma unroll
      for (int n = 0; n < 4; ++n) {
        const int c = col0 + n * 16 + lr;
        float v = fmaxf(acc[m][n][j] + (float)p1r[c] + (float)p3r[c], 0.f);
        int byte = (rl * 256 + c * 2) ^ ((rl & 7) << 4);
        *(__bf16*)(buf + byte) = (__bf16)v;
      }
    }
  }
  __syncthreads();

  // MFMA2: fused = h1 @ W2 + b2
  float b2v[4];
#pragma unroll
  for (int n = 0; n < 4; ++n) b2v[n] = b2[col0 + n * 16 + lr];
  f32x4 acc2[2][4] = {};
#pragma unroll
  for (int kk = 0; kk < 4; ++kk) {
    const int k0 = kk * 32 + lk;
    bf16x8 a[2], bm[4];
#pragma unroll
    for (int m = 0; m < 2; ++m) a[m] = read_a_frag(buf, wr * 32 + m * 16 + lr, k0);
#pragma unroll
    for (int n = 0; n < 4; ++n) bm[n] = *(const bf16x8*)(W2T + (size_t)(col0 + n * 16 + lr) * D + k0);
#pragma unroll
    for (int m = 0; m < 2; ++m)
#pragma unroll
      for (int n = 0; n < 4; ++n)
        acc2[m][n] = MFMA(a[m], bm[n], acc2[m][n]);
  }
#pragma unroll
  for (int m = 0; m < 2; ++m)
#pragma unroll
    for (int j = 0; j < 4; ++j) {
      int rl = wr * 32 + m * 16 + rr + j;
      int e = eb + rl;
#pragma unroll
      for (int n = 0; n < 4; ++n) {
        int c = col0 + n * 16 + lr;
        out_fused[(size_t)e * D + c] = acc2[m][n][j] + b2v[n];
      }
    }
}

// ---- attn chunk pipeline macros (static reg indexing only) ---------------
// KV row interleaved: lane l32 loads ONE 16B dwordx4 = {k4|v4} per edge.
#define LD1(P, K, J, SV)                                                     \
  do {                                                                       \
    const int jj_ = (J);                                                     \
    const int jc_ = jj_ < jm ? jj_ : 0;                                      \
    int si_ = __shfl((SV), jj_ & 31, 32);                                    \
    si_ = jj_ < jm ? si_ : 0;                                                \
    kv##P[K] = *(const bf16x8*)(KV + (size_t)si_ * 256 + (l32 << 3));        \
    ee##P[K] = *(const f32x4*)(edge + (size_t)(s0 + jc_) * D + (l32 << 2));  \
  } while (0)

#define LOADC(P, C)                                                          \
  do {                                                                       \
    const int c4_ = (C) * 4;                                                 \
    const int sv_ = (c4_ < 32) ? sidx0 : sidx1;                              \
    LD1(P, 0, c4_ + 0, sv_); LD1(P, 1, c4_ + 1, sv_);                        \
    LD1(P, 2, c4_ + 2, sv_); LD1(P, 3, c4_ + 3, sv_);                        \
  } while (0)

#define CP1(P, K, J)                                                         \
  do {                                                                       \
    const int jj_ = (J);                                                     \
    f32x4 ef_ = ee##P[K];                                                    \
    float x0_ = (float)kv##P[K][0] + ef_[0];                                 \
    float x1_ = (float)kv##P[K][1] + ef_[1];                                 \
    float x2_ = (float)kv##P[K][2] + ef_[2];                                 \
    float x3_ = (float)kv##P[K][3] + ef_[3];                                 \
    float pp_ = fmaf(qs[1], x1_, qs[0] * x0_) + fmaf(qs[3], x3_, qs[2] * x2_); \
    float s_ = red32(pp_);                                                   \
    float w_ = jj_ < jm ? exp2f(s_) : 0.f;                                   \
    l += w_;                                                                 \
    a[0] = fmaf(w_, (float)kv##P[K][4] + ef_[0], a[0]);                      \
    a[1] = fmaf(w_, (float)kv##P[K][5] + ef_[1], a[1]);                      \
    a[2] = fmaf(w_, (float)kv##P[K][6] + ef_[2], a[2]);                      \
    a[3] = fmaf(w_, (float)kv##P[K][7] + ef_[3], a[3]);                      \
  } while (0)

#define COMPC(P, C)                                                          \
  do {                                                                       \
    const int cc4_ = (C) * 4;                                                \
    CP1(P, 0, cc4_ + 0); CP1(P, 1, cc4_ + 1);                                \
    CP1(P, 2, cc4_ + 2); CP1(P, 3, cc4_ + 3);                                \
  } while (0)

// ---- ATTENTION kernel (R7 path standalone; 8 nodes/block, 8 KB LDS) ------
__global__ __launch_bounds__(256) __attribute__((amdgpu_waves_per_eu(3)))
void attn_node(
    const float* __restrict__ edge,
    const int* __restrict__ src,
    const float* __restrict__ Q,
    const __bf16* __restrict__ KV,
    const int* __restrict__ offs,
    const __bf16* __restrict__ WoT,
    const float* __restrict__ noderep,
    const float* __restrict__ gamma,
    const float* __restrict__ beta,
    float* __restrict__ out_updated) {
  __shared__ __align__(16) char buf[8192];  // [0,4K) agg tile | [4K,8K) xl f32
  const int tid = threadIdx.x;
  const int nw = tid >> 5;                  // node-slot 0..7 (32-lane halves)
  const int node = blockIdx.x * 8 + nw;     // 6250*8 = 50000
  const int l32 = tid & 31;
  int s0 = offs[node], s1 = offs[node + 1];
  int cnt = s1 - s0;
  // Q pre-scaled by CATT in prep (folded into Wq)
  f32x4 qs = *(const f32x4*)(Q + (size_t)node * D + l32 * 4);
  float l = 0.f;
  f32x4 a = {0.f, 0.f, 0.f, 0.f};

  const int jm = cnt < 64 ? cnt : 64;
  if (jm > 0) {
    // contiguous src indices: coalesced vector preload
    int sidx0 = 0, sidx1 = 0;
    if (l32 < cnt) sidx0 = src[s0 + l32];
    if (l32 + 32 < cnt) sidx1 = src[s0 + 32 + l32];
    bf16x8 kv0[4], kv1[4];
    f32x4 ee0[4], ee1[4];
    const int nch = (jm + 3) >> 2;
    LOADC(0, 0);
    for (int c = 0; c < nch; c += 2) {
      if (c + 1 < nch) LOADC(1, c + 1);
      COMPC(0, c);
      if (c + 2 < nch) LOADC(0, c + 2);
      if (c + 1 < nch) COMPC(1, c + 1);
    }
    // remainder (cnt > 64): statistically never taken
    for (int i = 64; i < cnt; ++i) {
      int si = src[s0 + i];
      bf16x8 kvx = *(const bf16x8*)(KV + (size_t)si * 256 + (l32 << 3));
      f32x4 ef = *(const f32x4*)(edge + (size_t)(s0 + i) * D + (l32 << 2));
      float x0 = (float)kvx[0] + ef[0], x1 = (float)kvx[1] + ef[1];
      float x2 = (float)kvx[2] + ef[2], x3 = (float)kvx[3] + ef[3];
      float pp = fmaf(qs[1], x1, qs[0] * x0) + fmaf(qs[3], x3, qs[2] * x2);
      float w = exp2f(red32(pp));
      l += w;
      a[0] = fmaf(w, (float)kvx[4] + ef[0], a[0]);
      a[1] = fmaf(w, (float)kvx[5] + ef[1], a[1]);
      a[2] = fmaf(w, (float)kvx[6] + ef[2], a[2]);
      a[3] = fmaf(w, (float)kvx[7] + ef[3], a[3]);
    }
  }
  float inv = l > 0.f ? 1.f / l : 0.f;
  f32x4 r;
  r[0] = a[0] * inv; r[1] = a[1] * inv; r[2] = a[2] * inv; r[3] = a[3] * inv;

  // ---- agg row -> swizzled bf16 LDS (row nw of a 16-row A tile) ----------
  {
    bf16x4 rb;
    rb[0] = (__bf16)r[0]; rb[1] = (__bf16)r[1];
    rb[2] = (__bf16)r[2]; rb[3] = (__bf16)r[3];
    int byte = (nw * 256 + l32 * 8) ^ ((nw & 7) << 4);
    *(bf16x4*)(buf + byte) = rb;
  }
  __syncthreads();

  // ---- Wo GEMM: rows 0..7 of aggTile @ Wo; cols split 2 n-tiles/wave -----
  // Rows 8..15 of the A tile are stale; MFMA output row r depends only on
  // A row r, so rows 0..7 of the product are exact.
  {
    const int wave = tid >> 6;
    const int lane = tid & 63;
    const int lr = lane & 15;
    const int lk = (lane >> 4) << 3;
    f32x4 acc[2] = {};
#pragma unroll
    for (int kk = 0; kk < 4; ++kk) {
      int k0 = kk * 32 + lk;
      bf16x8 af = read_a_frag(buf, lr, k0);
#pragma unroll
      for (int tt = 0; tt < 2; ++tt) {
        int nn = wave * 2 + tt;
        bf16x8 bm = *(const bf16x8*)(WoT + (size_t)(nn * 16 + lr) * D + k0);
        acc[tt] = MFMA(af, bm, acc[tt]);
      }
    }
    float* xl = (float*)(buf + 4096);  // [8][128]
    const int rr = (lane >> 4) * 4;
    if (rr < 8) {
#pragma unroll
      for (int tt = 0; tt < 2; ++tt) {
        int nn = wave * 2 + tt;
#pragma unroll
        for (int j = 0; j < 4; ++j)
          xl[(rr + j) * 128 + nn * 16 + lr] = acc[tt][j];
      }
    }
  }
  __syncthreads();

  // ---- LN per node-slot: updated = LN(node + aggWo) ----------------------
  {
    const float* xl = (const float*)(buf + 4096);
    f32x4 xv = *(const f32x4*)(xl + nw * 128 + l32 * 4);
    f32x4 nv = *(const f32x4*)(noderep + (size_t)node * D + l32 * 4);
    float x0 = xv[0] + nv[0], x1 = xv[1] + nv[1];
    float x2 = xv[2] + nv[2], x3 = xv[3] + nv[3];
    float s = red32(x0 + x1 + x2 + x3);
    float mu = s * (1.f / 128.f);
    float d0 = x0 - mu, d1 = x1 - mu, d2 = x2 - mu, d3 = x3 - mu;
    float vv = red32(d0 * d0 + d1 * d1 + d2 * d2 + d3 * d3);
    float rstd = rsqrtf(vv * (1.f / 128.f) + 1e-5f);
    f32x4 g = *(const f32x4*)(gamma + l32 * 4);
    f32x4 bb = *(const f32x4*)(beta + l32 * 4);
    f32x4 o;
    o[0] = d0 * rstd * g[0] + bb[0];
    o[1] = d1 * rstd * g[1] + bb[1];
    o[2] = d2 * rstd * g[2] + bb[2];
    o[3] = d3 * rstd * g[3] + bb[3];
    *(f32x4*)(out_updated + (size_t)node * D + l32 * 4) = o;
  }
}

// ---- launch ---------------------------------------------------------------
extern "C" void kernel_launch(void* const* d_in, const int* in_sizes, int n_in,
                              void* d_out, int out_size, void* d_ws, size_t ws_size,
                              hipStream_t stream) {
  const float* node = (const float*)d_in[0];
  const float* edge = (const float*)d_in[1];
  const int* src = (const int*)d_in[2];
  const int* dst = (const int*)d_in[3];
  const float* Wq = (const float*)d_in[4];
  const float* Wk = (const float*)d_in[5];
  const float* Wv = (const float*)d_in[6];
  const float* Wo = (const float*)d_in[7];
  const float* gamma = (const float*)d_in[8];
  const float* beta = (const float*)d_in[9];
  const float* W1 = (const float*)d_in[10];
  const float* b1 = (const float*)d_in[11];
  const float* W2 = (const float*)d_in[12];
  const float* b2 = (const float*)d_in[13];

  float* out_updated = (float*)d_out;
  float* out_fused = (float*)d_out + (size_t)NN * D;

  char* ws = (char*)d_ws;
  size_t o = 0;
  auto take = [&](size_t bytes) {
    char* p = ws + o;
    o = (o + bytes + 255) & ~(size_t)255;
    return p;
  };
  int* offs = (int*)take((NN + 1) * sizeof(int));
  __bf16* WqT = (__bf16*)take(128 * 128 * 2);
  __bf16* WkT = (__bf16*)take(128 * 128 * 2);
  __bf16* WvT = (__bf16*)take(128 * 128 * 2);
  __bf16* WoT = (__bf16*)take(128 * 128 * 2);
  __bf16* W1aT = (__bf16*)take(128 * 128 * 2);
  __bf16* W1bT = (__bf16*)take(128 * 128 * 2);
  __bf16* W1cT = (__bf16*)take(128 * 128 * 2);
  __bf16* W2T = (__bf16*)take(128 * 128 * 2);
  float* Qb = (float*)take((size_t)NN * D * 4);
  __bf16* KVb = (__bf16*)take((size_t)NN * 256 * 2);  // interleaved {k4|v4}
  __bf16* P1b = (__bf16*)take((size_t)NN * D * 2);
  __bf16* P3b = (__bf16*)take((size_t)NN * D * 2);

  PrepArgs pa;
  pa.W[0] = Wq; pa.WT[0] = WqT;
  pa.W[1] = Wk; pa.WT[1] = WkT;
  pa.W[2] = Wv; pa.WT[2] = WvT;
  pa.W[3] = Wo; pa.WT[3] = WoT;
  pa.W[4] = W1; pa.WT[4] = W1aT;
  pa.W[5] = W1 + 128 * 128; pa.WT[5] = W1bT;
  pa.W[6] = W1 + 256 * 128; pa.WT[6] = W1cT;
  pa.W[7] = W2; pa.WT[7] = W2T;
  pa.dst = dst; pa.offs = offs;
  prep_all<<<512 + (NN + 256) / 256, 256, 0, stream>>>(pa);

  int gnode = (NN + 127) / 128;
  GemmBatch gb;
  gb.BT[0] = WqT;  gb.C[0] = Qb;  gb.bias[0] = nullptr; gb.mode[0] = 0;
  gb.BT[1] = WkT;  gb.C[1] = KVb; gb.bias[1] = nullptr; gb.mode[1] = 2;
  gb.BT[2] = WvT;  gb.C[2] = KVb; gb.bias[2] = nullptr; gb.mode[2] = 3;
  gb.BT[3] = W1aT; gb.C[3] = P1b; gb.bias[3] = b1;      gb.mode[3] = 1;
  gb.BT[4] = W1cT; gb.C[4] = P3b; gb.bias[4] = nullptr; gb.mode[4] = 1;
  gemm_k128_b<<<dim3(gnode, 5), 256, 0, stream>>>(node, gb, NN);

  // SPLIT dispatches: per-path occupancy + per-path rocprof visibility.
  edge_mlp<<<NE / 64, 256, 0, stream>>>(edge, W1bT, W2T, P1b, P3b, dst, src,
                                        b2, out_fused);
  attn_node<<<NN / 8, 256, 0, stream>>>(edge, src, Qb, KVb, offs,
                                        WoT, node, gamma, beta, out_updated);
}

// Round 11
// 462.443 us; speedup vs baseline: 1.7174x; 1.0186x over previous
//
#include <hip/hip_runtime.h>
#include <hip/hip_bf16.h>

#define NN 50000
#define NE 600000
#define D 128

typedef __bf16 bf16x8 __attribute__((ext_vector_type(8)));
typedef __bf16 bf16x4 __attribute__((ext_vector_type(4)));
typedef float f32x4 __attribute__((ext_vector_type(4)));

#define MFMA(a, b, c) __builtin_amdgcn_mfma_f32_16x16x32_bf16((a), (b), (c), 0, 0, 0)

// ---- helpers -------------------------------------------------------------

// async 16B global->LDS (per-lane global addr, wave-uniform LDS base + lane*16)
static __device__ __forceinline__ void gload_lds16(const void* g, void* l) {
  __builtin_amdgcn_global_load_lds(
      (const __attribute__((address_space(1))) unsigned int*)g,
      (__attribute__((address_space(3))) unsigned int*)l, 16, 0, 0);
}

// Load 8 consecutive f32 along K from a row-major matrix, convert to bf16.
static __device__ __forceinline__ bf16x8 load_a_frag_nc(const float* __restrict__ A,
                                                        int row, int k0) {
  const f32x4* p = (const f32x4*)(A + (size_t)row * D + k0);
  f32x4 v0 = p[0], v1 = p[1];
  bf16x8 r;
  r[0] = (__bf16)v0[0]; r[1] = (__bf16)v0[1]; r[2] = (__bf16)v0[2]; r[3] = (__bf16)v0[3];
  r[4] = (__bf16)v1[0]; r[5] = (__bf16)v1[1]; r[6] = (__bf16)v1[2]; r[7] = (__bf16)v1[3];
  return r;
}

// Stage a 128-row f32 [M][128] tile into XOR-swizzled bf16 LDS (32 KB).
static __device__ __forceinline__ void stage_a_tile128(const float* __restrict__ A, int M,
                                                       int row_base, char* lds, int tid) {
  const int l32 = tid & 31;
  const int g = tid >> 5;
#pragma unroll
  for (int it = 0; it < 16; ++it) {
    int rl = it * 8 + g;
    int r = row_base + rl;
    f32x4 v = {};
    if (r < M) v = *(const f32x4*)(A + (size_t)r * D + l32 * 4);
    bf16x4 b;
    b[0] = (__bf16)v[0]; b[1] = (__bf16)v[1]; b[2] = (__bf16)v[2]; b[3] = (__bf16)v[3];
    int byte = (rl * 256 + l32 * 8) ^ ((rl & 7) << 4);
    *(bf16x4*)(lds + byte) = b;
  }
}

// Read a bf16x8 A-fragment (row rl, k-offset k0) from a swizzled tile.
static __device__ __forceinline__ bf16x8 read_a_frag(const char* lds, int rl, int k0) {
  int byte = (rl * 256 + k0 * 2) ^ ((rl & 7) << 4);
  return *(const bf16x8*)(lds + byte);
}

// DPP add: x + dpp_perm(x). VALU-pipe cross-lane (no LDS latency).
template <int CTRL>
static __device__ __forceinline__ float dpp_add(float x) {
  int v = __builtin_amdgcn_update_dpp(0, __float_as_int(x), CTRL, 0xf, 0xf, true);
  return x + __int_as_float(v);
}

// Sum across each 32-lane half; result in ALL lanes of the half.
static __device__ __forceinline__ float red32(float x) {
  x = dpp_add<0xB1>(x);    // quad xor1
  x = dpp_add<0x4E>(x);    // quad xor2
  x = dpp_add<0x124>(x);   // row_ror:4
  x = dpp_add<0x128>(x);   // row_ror:8
  return x + __shfl_xor(x, 16, 64);
}

// scale * log2(e): exp2(dot * CATT) == exp(dot / sqrt(128))
#define CATT 0.12751744612764933f

// ---- merged prep: 8 weight transposes + segment offsets, one launch ------
struct PrepArgs {
  const float* W[8];
  __bf16* WT[8];
  const int* dst;
  int* offs;
};

__global__ void prep_all(PrepArgs pa) {
  int b = blockIdx.x;
  if (b < 512) {
    int w = b >> 6;
    int t = (b & 63) * 256 + threadIdx.x;  // 16384 per weight
    int n = t & 127, k = t >> 7;
    float v = pa.W[w][k * 128 + n];
    if (w == 0) v *= CATT;  // fold softmax scale into Wq
    pa.WT[w][n * 128 + k] = (__bf16)v;
  } else {
    int n = (b - 512) * 256 + threadIdx.x;
    if (n > NN) return;
    int lo = 0, hi = NE;
    while (lo < hi) {
      int mid = (lo + hi) >> 1;
      if (pa.dst[mid] < n) lo = mid + 1; else hi = mid;
    }
    pa.offs[n] = lo;
  }
}

// ---- batched C[M,128] = A[M,128] @ B_i[128,128] for 5 weights ------------
// mode: 0 = f32 row, 1 = bf16 row,
//       2 = KV interleaved K (elem g*8+slot), 3 = KV interleaved V (+4).
struct GemmBatch {
  const __bf16* BT[5];
  void* C[5];
  const float* bias[5];  // nullptr = none
  int mode[5];
};

__global__ __launch_bounds__(256) void gemm_k128_b(const float* __restrict__ A,
                                                   GemmBatch gb, int M) {
  __shared__ __align__(16) char atile[128 * 256];
  const int y = blockIdx.y;
  const __bf16* __restrict__ BT = gb.BT[y];
  const int tid = threadIdx.x;
  const int lane = tid & 63;
  const int wave = tid >> 6;
  const int wr = wave >> 1, wc = wave & 1;
  const int row0 = blockIdx.x * 128;
  const int col0 = wc * 64;
  const int lr = lane & 15;
  const int lk = (lane >> 4) << 3;

  stage_a_tile128(A, M, row0, atile, tid);
  __syncthreads();

  f32x4 acc[4][4] = {};
#pragma unroll
  for (int kk = 0; kk < 4; ++kk) {
    const int k0 = kk * 32 + lk;
    bf16x8 a[4], b[4];
#pragma unroll
    for (int m = 0; m < 4; ++m) a[m] = read_a_frag(atile, wr * 64 + m * 16 + lr, k0);
#pragma unroll
    for (int n = 0; n < 4; ++n) b[n] = *(const bf16x8*)(BT + (size_t)(col0 + n * 16 + lr) * D + k0);
#pragma unroll
    for (int m = 0; m < 4; ++m)
#pragma unroll
      for (int n = 0; n < 4; ++n)
        acc[m][n] = MFMA(a[m], b[n], acc[m][n]);
  }
  const int rr = (lane >> 4) * 4;
  float bv[4] = {0.f, 0.f, 0.f, 0.f};
  if (gb.bias[y]) {
#pragma unroll
    for (int n = 0; n < 4; ++n) bv[n] = gb.bias[y][col0 + n * 16 + lr];
  }
  const int mode = gb.mode[y];
#pragma unroll
  for (int m = 0; m < 4; ++m)
#pragma unroll
    for (int j = 0; j < 4; ++j) {
      const int row = row0 + wr * 64 + m * 16 + rr + j;
      if (row < M) {
#pragma unroll
        for (int n = 0; n < 4; ++n) {
          const int c = col0 + n * 16 + lr;
          const float val = acc[m][n][j] + bv[n];
          if (mode == 0) {
            ((float*)gb.C[y])[(size_t)row * D + c] = val;
          } else if (mode == 1) {
            ((__bf16*)gb.C[y])[(size_t)row * D + c] = (__bf16)val;
          } else {
            // interleaved KV row: 32 groups of {k0..3, v0..3}
            const int e = ((c >> 2) << 3) + (c & 3) + (mode == 3 ? 4 : 0);
            ((__bf16*)gb.C[y])[(size_t)row * 256 + e] = (__bf16)val;
          }
        }
      }
    }
}

// ---- EDGE MLP kernel: async-DMA gathers (R0 pattern), XCD-affine grid ----
// Gathers (32 KB/block) issued at block start via global_load_lds: bytes in
// flight without VGPR/wave cost -> ~160 KB/CU outstanding vs ~8 KB with
// register-held loads (R10's 1.75 TB/s cause). One drain barrier after
// MFMA1 (which covers the latency), fold from LDS, h1 in-place, MFMA2.
__global__ __launch_bounds__(256) void edge_mlp(
    const float* __restrict__ edge,
    const __bf16* __restrict__ W1bT,
    const __bf16* __restrict__ W2T,
    const __bf16* __restrict__ P1,
    const __bf16* __restrict__ P3,
    const int* __restrict__ dst,
    const int* __restrict__ src,
    const float* __restrict__ b2,
    float* __restrict__ out_fused) {
  __shared__ __align__(16) char bufA[64 * 256];  // P1g -> h1
  __shared__ __align__(16) char bufB[64 * 256];  // P3g
  const int tid = threadIdx.x;
  // XCD-affine chunked (bijective over 9376=8*1172): each XCD gets a
  // contiguous block range -> its P1-gather working set (dst-sorted,
  // 12.8MB/8 = 1.6MB) fits the XCD's 4MB L2.
  const int swz = (blockIdx.x & 7) * 1172 + (blockIdx.x >> 3);
  if (swz >= NE / 64) return;
  const int eb = swz * 64;
  const int lane = tid & 63;
  const int wave = tid >> 6;
  const int wr = wave >> 1, wc = wave & 1;
  const int lr = lane & 15;
  const int lk = (lane >> 4) << 3;
  const int col0 = wc * 64;
  const int rr = (lane >> 4) * 4;

  // 1) async gathers FIRST: each wave covers rows wave*16 .. wave*16+15.
  // Per-lane pre-swizzled GLOBAL source + linear LDS dest (verified R0).
  {
    const int gr = lane >> 4;
    const int slot = lane & 15;
    int di[4], sg[4];
#pragma unroll
    for (int c = 0; c < 4; ++c) {
      int rl = wave * 16 + c * 4 + gr;
      di[c] = dst[eb + rl];
      sg[c] = src[eb + rl];
    }
#pragma unroll
    for (int c = 0; c < 4; ++c) {
      int rl = wave * 16 + c * 4 + gr;
      int sb = (slot * 16) ^ ((rl & 7) << 4);
      gload_lds16((const char*)(P1 + (size_t)di[c] * D) + sb,
                  bufA + (wave * 16 + c * 4) * 256);
      gload_lds16((const char*)(P3 + (size_t)sg[c] * D) + sb,
                  bufB + (wave * 16 + c * 4) * 256);
    }
  }

  // 2) MFMA1: acc = edge @ W1b (A-frags direct from global; covers latency)
  f32x4 acc[2][4] = {};
#pragma unroll
  for (int kk = 0; kk < 4; ++kk) {
    const int k0 = kk * 32 + lk;
    bf16x8 a[2], bm[4];
#pragma unroll
    for (int m = 0; m < 2; ++m) a[m] = load_a_frag_nc(edge, eb + wr * 32 + m * 16 + lr, k0);
#pragma unroll
    for (int n = 0; n < 4; ++n) bm[n] = *(const bf16x8*)(W1bT + (size_t)(col0 + n * 16 + lr) * D + k0);
#pragma unroll
    for (int m = 0; m < 2; ++m)
#pragma unroll
      for (int n = 0; n < 4; ++n)
        acc[m][n] = MFMA(a[m], bm[n], acc[m][n]);
  }
  __syncthreads();  // drains vmcnt(0): all gathers landed

  // 3) fold + ReLU + h1 in-place (same thread reads byte then writes it)
#pragma unroll
  for (int m = 0; m < 2; ++m) {
#pragma unroll
    for (int j = 0; j < 4; ++j) {
      const int rl = wr * 32 + m * 16 + rr + j;
#pragma unroll
      for (int n = 0; n < 4; ++n) {
        const int c = col0 + n * 16 + lr;
        int byte = (rl * 256 + c * 2) ^ ((rl & 7) << 4);
        float g1 = (float)*(const __bf16*)(bufA + byte);
        float g3 = (float)*(const __bf16*)(bufB + byte);
        float v = fmaxf(acc[m][n][j] + g1 + g3, 0.f);
        *(__bf16*)(bufA + byte) = (__bf16)v;
      }
    }
  }
  __syncthreads();

  // 4) MFMA2: fused = h1 @ W2 + b2
  float b2v[4];
#pragma unroll
  for (int n = 0; n < 4; ++n) b2v[n] = b2[col0 + n * 16 + lr];
  f32x4 acc2[2][4] = {};
#pragma unroll
  for (int kk = 0; kk < 4; ++kk) {
    const int k0 = kk * 32 + lk;
    bf16x8 a[2], bm[4];
#pragma unroll
    for (int m = 0; m < 2; ++m) a[m] = read_a_frag(bufA, wr * 32 + m * 16 + lr, k0);
#pragma unroll
    for (int n = 0; n < 4; ++n) bm[n] = *(const bf16x8*)(W2T + (size_t)(col0 + n * 16 + lr) * D + k0);
#pragma unroll
    for (int m = 0; m < 2; ++m)
#pragma unroll
      for (int n = 0; n < 4; ++n)
        acc2[m][n] = MFMA(a[m], bm[n], acc2[m][n]);
  }
#pragma unroll
  for (int m = 0; m < 2; ++m)
#pragma unroll
    for (int j = 0; j < 4; ++j) {
      int rl = wr * 32 + m * 16 + rr + j;
      int e = eb + rl;
#pragma unroll
      for (int n = 0; n < 4; ++n) {
        int c = col0 + n * 16 + lr;
        out_fused[(size_t)e * D + c] = acc2[m][n][j] + b2v[n];
      }
    }
}

// ---- attn chunk pipeline macros (static reg indexing only) ---------------
// KV row interleaved: lane l32 loads ONE 16B dwordx4 = {k4|v4} per edge.
#define LD1(P, K, J, SV)                                                     \
  do {                                                                       \
    const int jj_ = (J);                                                     \
    const int jc_ = jj_ < jm ? jj_ : 0;                                      \
    int si_ = __shfl((SV), jj_ & 31, 32);                                    \
    si_ = jj_ < jm ? si_ : 0;                                                \
    kv##P[K] = *(const bf16x8*)(KV + (size_t)si_ * 256 + (l32 << 3));        \
    ee##P[K] = *(const f32x4*)(edge + (size_t)(s0 + jc_) * D + (l32 << 2));  \
  } while (0)

#define LOADC(P, C)                                                          \
  do {                                                                       \
    const int c4_ = (C) * 4;                                                 \
    const int sv_ = (c4_ < 32) ? sidx0 : sidx1;                              \
    LD1(P, 0, c4_ + 0, sv_); LD1(P, 1, c4_ + 1, sv_);                        \
    LD1(P, 2, c4_ + 2, sv_); LD1(P, 3, c4_ + 3, sv_);                        \
  } while (0)

#define CP1(P, K, J)                                                         \
  do {                                                                       \
    const int jj_ = (J);                                                     \
    f32x4 ef_ = ee##P[K];                                                    \
    float x0_ = (float)kv##P[K][0] + ef_[0];                                 \
    float x1_ = (float)kv##P[K][1] + ef_[1];                                 \
    float x2_ = (float)kv##P[K][2] + ef_[2];                                 \
    float x3_ = (float)kv##P[K][3] + ef_[3];                                 \
    float pp_ = fmaf(qs[1], x1_, qs[0] * x0_) + fmaf(qs[3], x3_, qs[2] * x2_); \
    float s_ = red32(pp_);                                                   \
    float w_ = jj_ < jm ? exp2f(s_) : 0.f;                                   \
    l += w_;                                                                 \
    a[0] = fmaf(w_, (float)kv##P[K][4] + ef_[0], a[0]);                      \
    a[1] = fmaf(w_, (float)kv##P[K][5] + ef_[1], a[1]);                      \
    a[2] = fmaf(w_, (float)kv##P[K][6] + ef_[2], a[2]);                      \
    a[3] = fmaf(w_, (float)kv##P[K][7] + ef_[3], a[3]);                      \
  } while (0)

#define COMPC(P, C)                                                          \
  do {                                                                       \
    const int cc4_ = (C) * 4;                                                \
    CP1(P, 0, cc4_ + 0); CP1(P, 1, cc4_ + 1);                                \
    CP1(P, 2, cc4_ + 2); CP1(P, 3, cc4_ + 3);                                \
  } while (0)

// ---- ATTENTION kernel (8 nodes/block, 8 KB LDS) --------------------------
__global__ __launch_bounds__(256) __attribute__((amdgpu_waves_per_eu(3)))
void attn_node(
    const float* __restrict__ edge,
    const int* __restrict__ src,
    const float* __restrict__ Q,
    const __bf16* __restrict__ KV,
    const int* __restrict__ offs,
    const __bf16* __restrict__ WoT,
    const float* __restrict__ noderep,
    const float* __restrict__ gamma,
    const float* __restrict__ beta,
    float* __restrict__ out_updated) {
  __shared__ __align__(16) char buf[8192];  // [0,4K) agg tile | [4K,8K) xl f32
  const int tid = threadIdx.x;
  const int nw = tid >> 5;                  // node-slot 0..7 (32-lane halves)
  const int node = blockIdx.x * 8 + nw;     // 6250*8 = 50000
  const int l32 = tid & 31;
  int s0 = offs[node], s1 = offs[node + 1];
  int cnt = s1 - s0;
  // Q pre-scaled by CATT in prep (folded into Wq)
  f32x4 qs = *(const f32x4*)(Q + (size_t)node * D + l32 * 4);
  float l = 0.f;
  f32x4 a = {0.f, 0.f, 0.f, 0.f};

  const int jm = cnt < 64 ? cnt : 64;
  if (jm > 0) {
    // contiguous src indices: coalesced vector preload
    int sidx0 = 0, sidx1 = 0;
    if (l32 < cnt) sidx0 = src[s0 + l32];
    if (l32 + 32 < cnt) sidx1 = src[s0 + 32 + l32];
    bf16x8 kv0[4], kv1[4];
    f32x4 ee0[4], ee1[4];
    const int nch = (jm + 3) >> 2;
    LOADC(0, 0);
    for (int c = 0; c < nch; c += 2) {
      if (c + 1 < nch) LOADC(1, c + 1);
      COMPC(0, c);
      if (c + 2 < nch) LOADC(0, c + 2);
      if (c + 1 < nch) COMPC(1, c + 1);
    }
    // remainder (cnt > 64): statistically never taken
    for (int i = 64; i < cnt; ++i) {
      int si = src[s0 + i];
      bf16x8 kvx = *(const bf16x8*)(KV + (size_t)si * 256 + (l32 << 3));
      f32x4 ef = *(const f32x4*)(edge + (size_t)(s0 + i) * D + (l32 << 2));
      float x0 = (float)kvx[0] + ef[0], x1 = (float)kvx[1] + ef[1];
      float x2 = (float)kvx[2] + ef[2], x3 = (float)kvx[3] + ef[3];
      float pp = fmaf(qs[1], x1, qs[0] * x0) + fmaf(qs[3], x3, qs[2] * x2);
      float w = exp2f(red32(pp));
      l += w;
      a[0] = fmaf(w, (float)kvx[4] + ef[0], a[0]);
      a[1] = fmaf(w, (float)kvx[5] + ef[1], a[1]);
      a[2] = fmaf(w, (float)kvx[6] + ef[2], a[2]);
      a[3] = fmaf(w, (float)kvx[7] + ef[3], a[3]);
    }
  }
  float inv = l > 0.f ? 1.f / l : 0.f;
  f32x4 r;
  r[0] = a[0] * inv; r[1] = a[1] * inv; r[2] = a[2] * inv; r[3] = a[3] * inv;

  // ---- agg row -> swizzled bf16 LDS (row nw of a 16-row A tile) ----------
  {
    bf16x4 rb;
    rb[0] = (__bf16)r[0]; rb[1] = (__bf16)r[1];
    rb[2] = (__bf16)r[2]; rb[3] = (__bf16)r[3];
    int byte = (nw * 256 + l32 * 8) ^ ((nw & 7) << 4);
    *(bf16x4*)(buf + byte) = rb;
  }
  __syncthreads();

  // ---- Wo GEMM: rows 0..7 of aggTile @ Wo; cols split 2 n-tiles/wave -----
  {
    const int wave = tid >> 6;
    const int lane = tid & 63;
    const int lr = lane & 15;
    const int lk = (lane >> 4) << 3;
    f32x4 acc[2] = {};
#pragma unroll
    for (int kk = 0; kk < 4; ++kk) {
      int k0 = kk * 32 + lk;
      bf16x8 af = read_a_frag(buf, lr, k0);
#pragma unroll
      for (int tt = 0; tt < 2; ++tt) {
        int nn = wave * 2 + tt;
        bf16x8 bm = *(const bf16x8*)(WoT + (size_t)(nn * 16 + lr) * D + k0);
        acc[tt] = MFMA(af, bm, acc[tt]);
      }
    }
    float* xl = (float*)(buf + 4096);  // [8][128]
    const int rr = (lane >> 4) * 4;
    if (rr < 8) {
#pragma unroll
      for (int tt = 0; tt < 2; ++tt) {
        int nn = wave * 2 + tt;
#pragma unroll
        for (int j = 0; j < 4; ++j)
          xl[(rr + j) * 128 + nn * 16 + lr] = acc[tt][j];
      }
    }
  }
  __syncthreads();

  // ---- LN per node-slot: updated = LN(node + aggWo) ----------------------
  {
    const float* xl = (const float*)(buf + 4096);
    f32x4 xv = *(const f32x4*)(xl + nw * 128 + l32 * 4);
    f32x4 nv = *(const f32x4*)(noderep + (size_t)node * D + l32 * 4);
    float x0 = xv[0] + nv[0], x1 = xv[1] + nv[1];
    float x2 = xv[2] + nv[2], x3 = xv[3] + nv[3];
    float s = red32(x0 + x1 + x2 + x3);
    float mu = s * (1.f / 128.f);
    float d0 = x0 - mu, d1 = x1 - mu, d2 = x2 - mu, d3 = x3 - mu;
    float vv = red32(d0 * d0 + d1 * d1 + d2 * d2 + d3 * d3);
    float rstd = rsqrtf(vv * (1.f / 128.f) + 1e-5f);
    f32x4 g = *(const f32x4*)(gamma + l32 * 4);
    f32x4 bb = *(const f32x4*)(beta + l32 * 4);
    f32x4 o;
    o[0] = d0 * rstd * g[0] + bb[0];
    o[1] = d1 * rstd * g[1] + bb[1];
    o[2] = d2 * rstd * g[2] + bb[2];
    o[3] = d3 * rstd * g[3] + bb[3];
    *(f32x4*)(out_updated + (size_t)node * D + l32 * 4) = o;
  }
}

// ---- launch ---------------------------------------------------------------
extern "C" void kernel_launch(void* const* d_in, const int* in_sizes, int n_in,
                              void* d_out, int out_size, void* d_ws, size_t ws_size,
                              hipStream_t stream) {
  const float* node = (const float*)d_in[0];
  const float* edge = (const float*)d_in[1];
  const int* src = (const int*)d_in[2];
  const int* dst = (const int*)d_in[3];
  const float* Wq = (const float*)d_in[4];
  const float* Wk = (const float*)d_in[5];
  const float* Wv = (const float*)d_in[6];
  const float* Wo = (const float*)d_in[7];
  const float* gamma = (const float*)d_in[8];
  const float* beta = (const float*)d_in[9];
  const float* W1 = (const float*)d_in[10];
  const float* b1 = (const float*)d_in[11];
  const float* W2 = (const float*)d_in[12];
  const float* b2 = (const float*)d_in[13];

  float* out_updated = (float*)d_out;
  float* out_fused = (float*)d_out + (size_t)NN * D;

  char* ws = (char*)d_ws;
  size_t o = 0;
  auto take = [&](size_t bytes) {
    char* p = ws + o;
    o = (o + bytes + 255) & ~(size_t)255;
    return p;
  };
  int* offs = (int*)take((NN + 1) * sizeof(int));
  __bf16* WqT = (__bf16*)take(128 * 128 * 2);
  __bf16* WkT = (__bf16*)take(128 * 128 * 2);
  __bf16* WvT = (__bf16*)take(128 * 128 * 2);
  __bf16* WoT = (__bf16*)take(128 * 128 * 2);
  __bf16* W1aT = (__bf16*)take(128 * 128 * 2);
  __bf16* W1bT = (__bf16*)take(128 * 128 * 2);
  __bf16* W1cT = (__bf16*)take(128 * 128 * 2);
  __bf16* W2T = (__bf16*)take(128 * 128 * 2);
  float* Qb = (float*)take((size_t)NN * D * 4);
  __bf16* KVb = (__bf16*)take((size_t)NN * 256 * 2);  // interleaved {k4|v4}
  __bf16* P1b = (__bf16*)take((size_t)NN * D * 2);
  __bf16* P3b = (__bf16*)take((size_t)NN * D * 2);

  PrepArgs pa;
  pa.W[0] = Wq; pa.WT[0] = WqT;
  pa.W[1] = Wk; pa.WT[1] = WkT;
  pa.W[2] = Wv; pa.WT[2] = WvT;
  pa.W[3] = Wo; pa.WT[3] = WoT;
  pa.W[4] = W1; pa.WT[4] = W1aT;
  pa.W[5] = W1 + 128 * 128; pa.WT[5] = W1bT;
  pa.W[6] = W1 + 256 * 128; pa.WT[6] = W1cT;
  pa.W[7] = W2; pa.WT[7] = W2T;
  pa.dst = dst; pa.offs = offs;
  prep_all<<<512 + (NN + 256) / 256, 256, 0, stream>>>(pa);

  int gnode = (NN + 127) / 128;
  GemmBatch gb;
  gb.BT[0] = WqT;  gb.C[0] = Qb;  gb.bias[0] = nullptr; gb.mode[0] = 0;
  gb.BT[1] = WkT;  gb.C[1] = KVb; gb.bias[1] = nullptr; gb.mode[1] = 2;
  gb.BT[2] = WvT;  gb.C[2] = KVb; gb.bias[2] = nullptr; gb.mode[2] = 3;
  gb.BT[3] = W1aT; gb.C[3] = P1b; gb.bias[3] = b1;      gb.mode[3] = 1;
  gb.BT[4] = W1cT; gb.C[4] = P3b; gb.bias[4] = nullptr; gb.mode[4] = 1;
  gemm_k128_b<<<dim3(gnode, 5), 256, 0, stream>>>(node, gb, NN);

  // SPLIT dispatches (per-path rocprof visibility).
  // edge grid padded to 9376 = 8*1172 for the bijective XCD-affine swizzle.
  edge_mlp<<<9376, 256, 0, stream>>>(edge, W1bT, W2T, P1b, P3b, dst, src,
                                     b2, out_fused);
  attn_node<<<NN / 8, 256, 0, stream>>>(edge, src, Qb, KVb, offs,
                                        WoT, node, gamma, beta, out_updated);
}

// Round 12
// 442.513 us; speedup vs baseline: 1.7947x; 1.0450x over previous
//
#include <hip/hip_runtime.h>
#include <hip/hip_bf16.h>

#define NN 50000
#define NE 600000
#define D 128

typedef __bf16 bf16x8 __attribute__((ext_vector_type(8)));
typedef __bf16 bf16x4 __attribute__((ext_vector_type(4)));
typedef float f32x4 __attribute__((ext_vector_type(4)));

#define MFMA(a, b, c) __builtin_amdgcn_mfma_f32_16x16x32_bf16((a), (b), (c), 0, 0, 0)

// ---- helpers -------------------------------------------------------------

// async 16B global->LDS (per-lane global addr, wave-uniform LDS base + lane*16)
static __device__ __forceinline__ void gload_lds16(const void* g, void* l) {
  __builtin_amdgcn_global_load_lds(
      (const __attribute__((address_space(1))) unsigned int*)g,
      (__attribute__((address_space(3))) unsigned int*)l, 16, 0, 0);
}

// Stage a 64-row f32 [M][128] tile into XOR-swizzled bf16 LDS (16 KB).
// Cooperative: every thread issues independent coalesced 16B loads (the
// gemm staging pattern -- the only structure measured >3 TB/s here).
static __device__ __forceinline__ void stage_a_tile64(const float* __restrict__ A, int M,
                                                      int row_base, char* lds, int tid) {
  const int l32 = tid & 31;
  const int g = tid >> 5;
#pragma unroll
  for (int it = 0; it < 8; ++it) {
    int rl = it * 8 + g;
    int r = row_base + rl;
    f32x4 v = {};
    if (r < M) v = *(const f32x4*)(A + (size_t)r * D + l32 * 4);
    bf16x4 b;
    b[0] = (__bf16)v[0]; b[1] = (__bf16)v[1]; b[2] = (__bf16)v[2]; b[3] = (__bf16)v[3];
    int byte = (rl * 256 + l32 * 8) ^ ((rl & 7) << 4);
    *(bf16x4*)(lds + byte) = b;
  }
}

// Stage a 128-row f32 [M][128] tile into XOR-swizzled bf16 LDS (32 KB).
static __device__ __forceinline__ void stage_a_tile128(const float* __restrict__ A, int M,
                                                       int row_base, char* lds, int tid) {
  const int l32 = tid & 31;
  const int g = tid >> 5;
#pragma unroll
  for (int it = 0; it < 16; ++it) {
    int rl = it * 8 + g;
    int r = row_base + rl;
    f32x4 v = {};
    if (r < M) v = *(const f32x4*)(A + (size_t)r * D + l32 * 4);
    bf16x4 b;
    b[0] = (__bf16)v[0]; b[1] = (__bf16)v[1]; b[2] = (__bf16)v[2]; b[3] = (__bf16)v[3];
    int byte = (rl * 256 + l32 * 8) ^ ((rl & 7) << 4);
    *(bf16x4*)(lds + byte) = b;
  }
}

// Read a bf16x8 A-fragment (row rl, k-offset k0) from a swizzled tile.
static __device__ __forceinline__ bf16x8 read_a_frag(const char* lds, int rl, int k0) {
  int byte = (rl * 256 + k0 * 2) ^ ((rl & 7) << 4);
  return *(const bf16x8*)(lds + byte);
}

// DPP add: x + dpp_perm(x). VALU-pipe cross-lane (no LDS latency).
template <int CTRL>
static __device__ __forceinline__ float dpp_add(float x) {
  int v = __builtin_amdgcn_update_dpp(0, __float_as_int(x), CTRL, 0xf, 0xf, true);
  return x + __int_as_float(v);
}

// Sum across each 32-lane half; result in ALL lanes of the half.
static __device__ __forceinline__ float red32(float x) {
  x = dpp_add<0xB1>(x);    // quad xor1
  x = dpp_add<0x4E>(x);    // quad xor2
  x = dpp_add<0x124>(x);   // row_ror:4
  x = dpp_add<0x128>(x);   // row_ror:8
  return x + __shfl_xor(x, 16, 64);
}

// scale * log2(e): exp2(dot * CATT) == exp(dot / sqrt(128))
#define CATT 0.12751744612764933f

// ---- merged prep: 8 weight transposes + segment offsets, one launch ------
struct PrepArgs {
  const float* W[8];
  __bf16* WT[8];
  const int* dst;
  int* offs;
};

__global__ void prep_all(PrepArgs pa) {
  int b = blockIdx.x;
  if (b < 512) {
    int w = b >> 6;
    int t = (b & 63) * 256 + threadIdx.x;  // 16384 per weight
    int n = t & 127, k = t >> 7;
    float v = pa.W[w][k * 128 + n];
    if (w == 0) v *= CATT;  // fold softmax scale into Wq
    pa.WT[w][n * 128 + k] = (__bf16)v;
  } else {
    int n = (b - 512) * 256 + threadIdx.x;
    if (n > NN) return;
    int lo = 0, hi = NE;
    while (lo < hi) {
      int mid = (lo + hi) >> 1;
      if (pa.dst[mid] < n) lo = mid + 1; else hi = mid;
    }
    pa.offs[n] = lo;
  }
}

// ---- batched C[M,128] = A[M,128] @ B_i[128,128] for 5 weights ------------
// mode: 0 = f32 row, 1 = bf16 row,
//       2 = KV interleaved K (elem g*8+slot), 3 = KV interleaved V (+4).
struct GemmBatch {
  const __bf16* BT[5];
  void* C[5];
  const float* bias[5];  // nullptr = none
  int mode[5];
};

__global__ __launch_bounds__(256) void gemm_k128_b(const float* __restrict__ A,
                                                   GemmBatch gb, int M) {
  __shared__ __align__(16) char atile[128 * 256];
  const int y = blockIdx.y;
  const __bf16* __restrict__ BT = gb.BT[y];
  const int tid = threadIdx.x;
  const int lane = tid & 63;
  const int wave = tid >> 6;
  const int wr = wave >> 1, wc = wave & 1;
  const int row0 = blockIdx.x * 128;
  const int col0 = wc * 64;
  const int lr = lane & 15;
  const int lk = (lane >> 4) << 3;

  stage_a_tile128(A, M, row0, atile, tid);
  __syncthreads();

  f32x4 acc[4][4] = {};
#pragma unroll
  for (int kk = 0; kk < 4; ++kk) {
    const int k0 = kk * 32 + lk;
    bf16x8 a[4], b[4];
#pragma unroll
    for (int m = 0; m < 4; ++m) a[m] = read_a_frag(atile, wr * 64 + m * 16 + lr, k0);
#pragma unroll
    for (int n = 0; n < 4; ++n) b[n] = *(const bf16x8*)(BT + (size_t)(col0 + n * 16 + lr) * D + k0);
#pragma unroll
    for (int m = 0; m < 4; ++m)
#pragma unroll
      for (int n = 0; n < 4; ++n)
        acc[m][n] = MFMA(a[m], b[n], acc[m][n]);
  }
  const int rr = (lane >> 4) * 4;
  float bv[4] = {0.f, 0.f, 0.f, 0.f};
  if (gb.bias[y]) {
#pragma unroll
    for (int n = 0; n < 4; ++n) bv[n] = gb.bias[y][col0 + n * 16 + lr];
  }
  const int mode = gb.mode[y];
#pragma unroll
  for (int m = 0; m < 4; ++m)
#pragma unroll
    for (int j = 0; j < 4; ++j) {
      const int row = row0 + wr * 64 + m * 16 + rr + j;
      if (row < M) {
#pragma unroll
        for (int n = 0; n < 4; ++n) {
          const int c = col0 + n * 16 + lr;
          const float val = acc[m][n][j] + bv[n];
          if (mode == 0) {
            ((float*)gb.C[y])[(size_t)row * D + c] = val;
          } else if (mode == 1) {
            ((__bf16*)gb.C[y])[(size_t)row * D + c] = (__bf16)val;
          } else {
            // interleaved KV row: 32 groups of {k0..3, v0..3}
            const int e = ((c >> 2) << 3) + (c & 3) + (mode == 3 ? 4 : 0);
            ((__bf16*)gb.C[y])[(size_t)row * 256 + e] = (__bf16)val;
          }
        }
      }
    }
}

// ---- EDGE MLP kernel: gemm-style coop A-staging + async P3 gathers -------
// All streaming traffic is now either cooperative coalesced loads (edge
// tile, like gemm_k128_b -- the only pattern measured >3 TB/s here), async
// DMA (P3 random gathers), or L1-resident (weights, sorted-dst P1 rows).
// No register-held scattered global loads in the hot path.
__global__ __launch_bounds__(256) void edge_mlp(
    const float* __restrict__ edge,
    const __bf16* __restrict__ W1bT,
    const __bf16* __restrict__ W2T,
    const __bf16* __restrict__ P1,
    const __bf16* __restrict__ P3,
    const int* __restrict__ dst,
    const int* __restrict__ src,
    const float* __restrict__ b2,
    float* __restrict__ out_fused) {
  __shared__ __align__(16) char atile[64 * 256];  // edge bf16 swz -> h1
  __shared__ __align__(16) char bufP3[64 * 256];  // P3 gathers
  const int tid = threadIdx.x;
  // XCD-affine chunked (bijective over 9376=8*1172): contiguous block range
  // per XCD -> sorted-dst P1 slice (1.6 MB) L2-resident.
  const int swz = (blockIdx.x & 7) * 1172 + (blockIdx.x >> 3);
  if (swz >= NE / 64) return;
  const int eb = swz * 64;
  const int lane = tid & 63;
  const int wave = tid >> 6;
  const int wr = wave >> 1, wc = wave & 1;
  const int lr = lane & 15;
  const int lk = (lane >> 4) << 3;
  const int col0 = wc * 64;
  const int rr = (lane >> 4) * 4;

  // 1) async P3 gathers FIRST (deepest in flight; 0 VGPR cost).
  //    Per-lane pre-swizzled global source + linear LDS dest (R0-verified).
  {
    const int gr = lane >> 4;
    const int slot = lane & 15;
    int sg[4];
#pragma unroll
    for (int c = 0; c < 4; ++c) sg[c] = src[eb + wave * 16 + c * 4 + gr];
#pragma unroll
    for (int c = 0; c < 4; ++c) {
      int rl = wave * 16 + c * 4 + gr;
      int sb = (slot * 16) ^ ((rl & 7) << 4);
      gload_lds16((const char*)(P3 + (size_t)sg[c] * D) + sb,
                  bufP3 + (wave * 16 + c * 4) * 256);
    }
  }

  // 2) cooperative edge-tile staging (gemm pattern: independent coalesced
  //    16B loads, f32->bf16, swizzled LDS).
  stage_a_tile64(edge, NE, eb, atile, tid);
  __syncthreads();  // drains stage stores AND gather vmcnt

  // 3) MFMA1: acc = edge @ W1b (A from LDS, B from L1-resident weights)
  f32x4 acc[2][4] = {};
#pragma unroll
  for (int kk = 0; kk < 4; ++kk) {
    const int k0 = kk * 32 + lk;
    bf16x8 a[2], bm[4];
#pragma unroll
    for (int m = 0; m < 2; ++m) a[m] = read_a_frag(atile, wr * 32 + m * 16 + lr, k0);
#pragma unroll
    for (int n = 0; n < 4; ++n) bm[n] = *(const bf16x8*)(W1bT + (size_t)(col0 + n * 16 + lr) * D + k0);
#pragma unroll
    for (int m = 0; m < 2; ++m)
#pragma unroll
      for (int n = 0; n < 4; ++n)
        acc[m][n] = MFMA(a[m], bm[n], acc[m][n]);
  }
  __syncthreads();  // all atile reads done before h1 overwrites

  // 4) fold: h1 = relu(acc + P1[dst] + P3g); P1 rows are sorted-dst (~6
  //    distinct per tile, L1-hit); P3 from LDS. h1 -> atile (swizzled).
#pragma unroll
  for (int m = 0; m < 2; ++m) {
#pragma unroll
    for (int j = 0; j < 4; ++j) {
      const int rl = wr * 32 + m * 16 + rr + j;
      const __bf16* __restrict__ p1r = P1 + (size_t)dst[eb + rl] * D;
#pragma unroll
      for (int n = 0; n < 4; ++n) {
        const int c = col0 + n * 16 + lr;
        int byte = (rl * 256 + c * 2) ^ ((rl & 7) << 4);
        float g3 = (float)*(const __bf16*)(bufP3 + byte);
        float v = fmaxf(acc[m][n][j] + (float)p1r[c] + g3, 0.f);
        *(__bf16*)(atile + byte) = (__bf16)v;
      }
    }
  }
  __syncthreads();

  // 5) MFMA2: fused = h1 @ W2 + b2
  float b2v[4];
#pragma unroll
  for (int n = 0; n < 4; ++n) b2v[n] = b2[col0 + n * 16 + lr];
  f32x4 acc2[2][4] = {};
#pragma unroll
  for (int kk = 0; kk < 4; ++kk) {
    const int k0 = kk * 32 + lk;
    bf16x8 a[2], bm[4];
#pragma unroll
    for (int m = 0; m < 2; ++m) a[m] = read_a_frag(atile, wr * 32 + m * 16 + lr, k0);
#pragma unroll
    for (int n = 0; n < 4; ++n) bm[n] = *(const bf16x8*)(W2T + (size_t)(col0 + n * 16 + lr) * D + k0);
#pragma unroll
    for (int m = 0; m < 2; ++m)
#pragma unroll
      for (int n = 0; n < 4; ++n)
        acc2[m][n] = MFMA(a[m], bm[n], acc2[m][n]);
  }
#pragma unroll
  for (int m = 0; m < 2; ++m)
#pragma unroll
    for (int j = 0; j < 4; ++j) {
      int rl = wr * 32 + m * 16 + rr + j;
      int e = eb + rl;
#pragma unroll
      for (int n = 0; n < 4; ++n) {
        int c = col0 + n * 16 + lr;
        out_fused[(size_t)e * D + c] = acc2[m][n][j] + b2v[n];
      }
    }
}

// ---- attn chunk pipeline macros (static reg indexing only) ---------------
// KV row interleaved: lane l32 loads ONE 16B dwordx4 = {k4|v4} per edge.
#define LD1(P, K, J, SV)                                                     \
  do {                                                                       \
    const int jj_ = (J);                                                     \
    const int jc_ = jj_ < jm ? jj_ : 0;                                      \
    int si_ = __shfl((SV), jj_ & 31, 32);                                    \
    si_ = jj_ < jm ? si_ : 0;                                                \
    kv##P[K] = *(const bf16x8*)(KV + (size_t)si_ * 256 + (l32 << 3));        \
    ee##P[K] = *(const f32x4*)(edge + (size_t)(s0 + jc_) * D + (l32 << 2));  \
  } while (0)

#define LOADC(P, C)                                                          \
  do {                                                                       \
    const int c4_ = (C) * 4;                                                 \
    const int sv_ = (c4_ < 32) ? sidx0 : sidx1;                              \
    LD1(P, 0, c4_ + 0, sv_); LD1(P, 1, c4_ + 1, sv_);                        \
    LD1(P, 2, c4_ + 2, sv_); LD1(P, 3, c4_ + 3, sv_);                        \
  } while (0)

#define CP1(P, K, J)                                                         \
  do {                                                                       \
    const int jj_ = (J);                                                     \
    f32x4 ef_ = ee##P[K];                                                    \
    float x0_ = (float)kv##P[K][0] + ef_[0];                                 \
    float x1_ = (float)kv##P[K][1] + ef_[1];                                 \
    float x2_ = (float)kv##P[K][2] + ef_[2];                                 \
    float x3_ = (float)kv##P[K][3] + ef_[3];                                 \
    float pp_ = fmaf(qs[1], x1_, qs[0] * x0_) + fmaf(qs[3], x3_, qs[2] * x2_); \
    float s_ = red32(pp_);                                                   \
    float w_ = jj_ < jm ? exp2f(s_) : 0.f;                                   \
    l += w_;                                                                 \
    a[0] = fmaf(w_, (float)kv##P[K][4] + ef_[0], a[0]);                      \
    a[1] = fmaf(w_, (float)kv##P[K][5] + ef_[1], a[1]);                      \
    a[2] = fmaf(w_, (float)kv##P[K][6] + ef_[2], a[2]);                      \
    a[3] = fmaf(w_, (float)kv##P[K][7] + ef_[3], a[3]);                      \
  } while (0)

#define COMPC(P, C)                                                          \
  do {                                                                       \
    const int cc4_ = (C) * 4;                                                \
    CP1(P, 0, cc4_ + 0); CP1(P, 1, cc4_ + 1);                                \
    CP1(P, 2, cc4_ + 2); CP1(P, 3, cc4_ + 3);                                \
  } while (0)

// ---- ATTENTION kernel (8 nodes/block, 8 KB LDS) --------------------------
__global__ __launch_bounds__(256) __attribute__((amdgpu_waves_per_eu(3)))
void attn_node(
    const float* __restrict__ edge,
    const int* __restrict__ src,
    const float* __restrict__ Q,
    const __bf16* __restrict__ KV,
    const int* __restrict__ offs,
    const __bf16* __restrict__ WoT,
    const float* __restrict__ noderep,
    const float* __restrict__ gamma,
    const float* __restrict__ beta,
    float* __restrict__ out_updated) {
  __shared__ __align__(16) char buf[8192];  // [0,4K) agg tile | [4K,8K) xl f32
  const int tid = threadIdx.x;
  const int nw = tid >> 5;                  // node-slot 0..7 (32-lane halves)
  const int node = blockIdx.x * 8 + nw;     // 6250*8 = 50000
  const int l32 = tid & 31;
  int s0 = offs[node], s1 = offs[node + 1];
  int cnt = s1 - s0;
  // Q pre-scaled by CATT in prep (folded into Wq)
  f32x4 qs = *(const f32x4*)(Q + (size_t)node * D + l32 * 4);
  float l = 0.f;
  f32x4 a = {0.f, 0.f, 0.f, 0.f};

  const int jm = cnt < 64 ? cnt : 64;
  if (jm > 0) {
    // contiguous src indices: coalesced vector preload
    int sidx0 = 0, sidx1 = 0;
    if (l32 < cnt) sidx0 = src[s0 + l32];
    if (l32 + 32 < cnt) sidx1 = src[s0 + 32 + l32];
    bf16x8 kv0[4], kv1[4];
    f32x4 ee0[4], ee1[4];
    const int nch = (jm + 3) >> 2;
    LOADC(0, 0);
    for (int c = 0; c < nch; c += 2) {
      if (c + 1 < nch) LOADC(1, c + 1);
      COMPC(0, c);
      if (c + 2 < nch) LOADC(0, c + 2);
      if (c + 1 < nch) COMPC(1, c + 1);
    }
    // remainder (cnt > 64): statistically never taken
    for (int i = 64; i < cnt; ++i) {
      int si = src[s0 + i];
      bf16x8 kvx = *(const bf16x8*)(KV + (size_t)si * 256 + (l32 << 3));
      f32x4 ef = *(const f32x4*)(edge + (size_t)(s0 + i) * D + (l32 << 2));
      float x0 = (float)kvx[0] + ef[0], x1 = (float)kvx[1] + ef[1];
      float x2 = (float)kvx[2] + ef[2], x3 = (float)kvx[3] + ef[3];
      float pp = fmaf(qs[1], x1, qs[0] * x0) + fmaf(qs[3], x3, qs[2] * x2);
      float w = exp2f(red32(pp));
      l += w;
      a[0] = fmaf(w, (float)kvx[4] + ef[0], a[0]);
      a[1] = fmaf(w, (float)kvx[5] + ef[1], a[1]);
      a[2] = fmaf(w, (float)kvx[6] + ef[2], a[2]);
      a[3] = fmaf(w, (float)kvx[7] + ef[3], a[3]);
    }
  }
  float inv = l > 0.f ? 1.f / l : 0.f;
  f32x4 r;
  r[0] = a[0] * inv; r[1] = a[1] * inv; r[2] = a[2] * inv; r[3] = a[3] * inv;

  // ---- agg row -> swizzled bf16 LDS (row nw of a 16-row A tile) ----------
  {
    bf16x4 rb;
    rb[0] = (__bf16)r[0]; rb[1] = (__bf16)r[1];
    rb[2] = (__bf16)r[2]; rb[3] = (__bf16)r[3];
    int byte = (nw * 256 + l32 * 8) ^ ((nw & 7) << 4);
    *(bf16x4*)(buf + byte) = rb;
  }
  __syncthreads();

  // ---- Wo GEMM: rows 0..7 of aggTile @ Wo; cols split 2 n-tiles/wave -----
  {
    const int wave = tid >> 6;
    const int lane = tid & 63;
    const int lr = lane & 15;
    const int lk = (lane >> 4) << 3;
    f32x4 acc[2] = {};
#pragma unroll
    for (int kk = 0; kk < 4; ++kk) {
      int k0 = kk * 32 + lk;
      bf16x8 af = read_a_frag(buf, lr, k0);
#pragma unroll
      for (int tt = 0; tt < 2; ++tt) {
        int nn = wave * 2 + tt;
        bf16x8 bm = *(const bf16x8*)(WoT + (size_t)(nn * 16 + lr) * D + k0);
        acc[tt] = MFMA(af, bm, acc[tt]);
      }
    }
    float* xl = (float*)(buf + 4096);  // [8][128]
    const int rr = (lane >> 4) * 4;
    if (rr < 8) {
#pragma unroll
      for (int tt = 0; tt < 2; ++tt) {
        int nn = wave * 2 + tt;
#pragma unroll
        for (int j = 0; j < 4; ++j)
          xl[(rr + j) * 128 + nn * 16 + lr] = acc[tt][j];
      }
    }
  }
  __syncthreads();

  // ---- LN per node-slot: updated = LN(node + aggWo) ----------------------
  {
    const float* xl = (const float*)(buf + 4096);
    f32x4 xv = *(const f32x4*)(xl + nw * 128 + l32 * 4);
    f32x4 nv = *(const f32x4*)(noderep + (size_t)node * D + l32 * 4);
    float x0 = xv[0] + nv[0], x1 = xv[1] + nv[1];
    float x2 = xv[2] + nv[2], x3 = xv[3] + nv[3];
    float s = red32(x0 + x1 + x2 + x3);
    float mu = s * (1.f / 128.f);
    float d0 = x0 - mu, d1 = x1 - mu, d2 = x2 - mu, d3 = x3 - mu;
    float vv = red32(d0 * d0 + d1 * d1 + d2 * d2 + d3 * d3);
    float rstd = rsqrtf(vv * (1.f / 128.f) + 1e-5f);
    f32x4 g = *(const f32x4*)(gamma + l32 * 4);
    f32x4 bb = *(const f32x4*)(beta + l32 * 4);
    f32x4 o;
    o[0] = d0 * rstd * g[0] + bb[0];
    o[1] = d1 * rstd * g[1] + bb[1];
    o[2] = d2 * rstd * g[2] + bb[2];
    o[3] = d3 * rstd * g[3] + bb[3];
    *(f32x4*)(out_updated + (size_t)node * D + l32 * 4) = o;
  }
}

// ---- launch ---------------------------------------------------------------
extern "C" void kernel_launch(void* const* d_in, const int* in_sizes, int n_in,
                              void* d_out, int out_size, void* d_ws, size_t ws_size,
                              hipStream_t stream) {
  const float* node = (const float*)d_in[0];
  const float* edge = (const float*)d_in[1];
  const int* src = (const int*)d_in[2];
  const int* dst = (const int*)d_in[3];
  const float* Wq = (const float*)d_in[4];
  const float* Wk = (const float*)d_in[5];
  const float* Wv = (const float*)d_in[6];
  const float* Wo = (const float*)d_in[7];
  const float* gamma = (const float*)d_in[8];
  const float* beta = (const float*)d_in[9];
  const float* W1 = (const float*)d_in[10];
  const float* b1 = (const float*)d_in[11];
  const float* W2 = (const float*)d_in[12];
  const float* b2 = (const float*)d_in[13];

  float* out_updated = (float*)d_out;
  float* out_fused = (float*)d_out + (size_t)NN * D;

  char* ws = (char*)d_ws;
  size_t o = 0;
  auto take = [&](size_t bytes) {
    char* p = ws + o;
    o = (o + bytes + 255) & ~(size_t)255;
    return p;
  };
  int* offs = (int*)take((NN + 1) * sizeof(int));
  __bf16* WqT = (__bf16*)take(128 * 128 * 2);
  __bf16* WkT = (__bf16*)take(128 * 128 * 2);
  __bf16* WvT = (__bf16*)take(128 * 128 * 2);
  __bf16* WoT = (__bf16*)take(128 * 128 * 2);
  __bf16* W1aT = (__bf16*)take(128 * 128 * 2);
  __bf16* W1bT = (__bf16*)take(128 * 128 * 2);
  __bf16* W1cT = (__bf16*)take(128 * 128 * 2);
  __bf16* W2T = (__bf16*)take(128 * 128 * 2);
  float* Qb = (float*)take((size_t)NN * D * 4);
  __bf16* KVb = (__bf16*)take((size_t)NN * 256 * 2);  // interleaved {k4|v4}
  __bf16* P1b = (__bf16*)take((size_t)NN * D * 2);
  __bf16* P3b = (__bf16*)take((size_t)NN * D * 2);

  PrepArgs pa;
  pa.W[0] = Wq; pa.WT[0] = WqT;
  pa.W[1] = Wk; pa.WT[1] = WkT;
  pa.W[2] = Wv; pa.WT[2] = WvT;
  pa.W[3] = Wo; pa.WT[3] = WoT;
  pa.W[4] = W1; pa.WT[4] = W1aT;
  pa.W[5] = W1 + 128 * 128; pa.WT[5] = W1bT;
  pa.W[6] = W1 + 256 * 128; pa.WT[6] = W1cT;
  pa.W[7] = W2; pa.WT[7] = W2T;
  pa.dst = dst; pa.offs = offs;
  prep_all<<<512 + (NN + 256) / 256, 256, 0, stream>>>(pa);

  int gnode = (NN + 127) / 128;
  GemmBatch gb;
  gb.BT[0] = WqT;  gb.C[0] = Qb;  gb.bias[0] = nullptr; gb.mode[0] = 0;
  gb.BT[1] = WkT;  gb.C[1] = KVb; gb.bias[1] = nullptr; gb.mode[1] = 2;
  gb.BT[2] = WvT;  gb.C[2] = KVb; gb.bias[2] = nullptr; gb.mode[2] = 3;
  gb.BT[3] = W1aT; gb.C[3] = P1b; gb.bias[3] = b1;      gb.mode[3] = 1;
  gb.BT[4] = W1cT; gb.C[4] = P3b; gb.bias[4] = nullptr; gb.mode[4] = 1;
  gemm_k128_b<<<dim3(gnode, 5), 256, 0, stream>>>(node, gb, NN);

  // SPLIT dispatches (per-path rocprof visibility).
  // edge grid padded to 9376 = 8*1172 for the bijective XCD-affine swizzle.
  edge_mlp<<<9376, 256, 0, stream>>>(edge, W1bT, W2T, P1b, P3b, dst, src,
                                     b2, out_fused);
  attn_node<<<NN / 8, 256, 0, stream>>>(edge, src, Qb, KVb, offs,
                                        WoT, node, gamma, beta, out_updated);
}

// Round 13
// 401.307 us; speedup vs baseline: 1.9790x; 1.1027x over previous
//
#include <hip/hip_runtime.h>
#include <hip/hip_bf16.h>

#define NN 50000
#define NE 600000
#define D 128

typedef __bf16 bf16x8 __attribute__((ext_vector_type(8)));
typedef __bf16 bf16x4 __attribute__((ext_vector_type(4)));
typedef float f32x4 __attribute__((ext_vector_type(4)));

#define MFMA(a, b, c) __builtin_amdgcn_mfma_f32_16x16x32_bf16((a), (b), (c), 0, 0, 0)

// ---- helpers -------------------------------------------------------------

// async 16B global->LDS (per-lane global addr, wave-uniform LDS base + lane*16)
static __device__ __forceinline__ void gload_lds16(const void* g, void* l) {
  __builtin_amdgcn_global_load_lds(
      (const __attribute__((address_space(1))) unsigned int*)g,
      (__attribute__((address_space(3))) unsigned int*)l, 16, 0, 0);
}

// Stage a 64-row f32 [M][128] tile into XOR-swizzled bf16 LDS (16 KB).
// Cooperative gemm staging pattern (R12: the fix that beat per-lane loads).
static __device__ __forceinline__ void stage_a_tile64(const float* __restrict__ A, int M,
                                                      int row_base, char* lds, int tid) {
  const int l32 = tid & 31;
  const int g = tid >> 5;
#pragma unroll
  for (int it = 0; it < 8; ++it) {
    int rl = it * 8 + g;
    int r = row_base + rl;
    f32x4 v = {};
    if (r < M) v = *(const f32x4*)(A + (size_t)r * D + l32 * 4);
    bf16x4 b;
    b[0] = (__bf16)v[0]; b[1] = (__bf16)v[1]; b[2] = (__bf16)v[2]; b[3] = (__bf16)v[3];
    int byte = (rl * 256 + l32 * 8) ^ ((rl & 7) << 4);
    *(bf16x4*)(lds + byte) = b;
  }
}

// Stage a 128-row f32 [M][128] tile into XOR-swizzled bf16 LDS (32 KB).
static __device__ __forceinline__ void stage_a_tile128(const float* __restrict__ A, int M,
                                                       int row_base, char* lds, int tid) {
  const int l32 = tid & 31;
  const int g = tid >> 5;
#pragma unroll
  for (int it = 0; it < 16; ++it) {
    int rl = it * 8 + g;
    int r = row_base + rl;
    f32x4 v = {};
    if (r < M) v = *(const f32x4*)(A + (size_t)r * D + l32 * 4);
    bf16x4 b;
    b[0] = (__bf16)v[0]; b[1] = (__bf16)v[1]; b[2] = (__bf16)v[2]; b[3] = (__bf16)v[3];
    int byte = (rl * 256 + l32 * 8) ^ ((rl & 7) << 4);
    *(bf16x4*)(lds + byte) = b;
  }
}

// Read a bf16x8 A-fragment (row rl, k-offset k0) from a swizzled tile.
static __device__ __forceinline__ bf16x8 read_a_frag(const char* lds, int rl, int k0) {
  int byte = (rl * 256 + k0 * 2) ^ ((rl & 7) << 4);
  return *(const bf16x8*)(lds + byte);
}

// DPP add: x + dpp_perm(x). VALU-pipe cross-lane (no LDS latency).
template <int CTRL>
static __device__ __forceinline__ float dpp_add(float x) {
  int v = __builtin_amdgcn_update_dpp(0, __float_as_int(x), CTRL, 0xf, 0xf, true);
  return x + __int_as_float(v);
}

// Sum across each 32-lane half; result in ALL lanes of the half.
static __device__ __forceinline__ float red32(float x) {
  x = dpp_add<0xB1>(x);    // quad xor1
  x = dpp_add<0x4E>(x);    // quad xor2
  x = dpp_add<0x124>(x);   // row_ror:4
  x = dpp_add<0x128>(x);   // row_ror:8
  return x + __shfl_xor(x, 16, 64);
}

// scale * log2(e): exp2(dot * CATT) == exp(dot / sqrt(128))
#define CATT 0.12751744612764933f

// ---- merged prep: 8 weight transposes + segment offsets, one launch ------
struct PrepArgs {
  const float* W[8];
  __bf16* WT[8];
  const int* dst;
  int* offs;
};

__global__ void prep_all(PrepArgs pa) {
  int b = blockIdx.x;
  if (b < 512) {
    int w = b >> 6;
    int t = (b & 63) * 256 + threadIdx.x;  // 16384 per weight
    int n = t & 127, k = t >> 7;
    float v = pa.W[w][k * 128 + n];
    if (w == 0) v *= CATT;  // fold softmax scale into Wq
    pa.WT[w][n * 128 + k] = (__bf16)v;
  } else {
    int n = (b - 512) * 256 + threadIdx.x;
    if (n > NN) return;
    int lo = 0, hi = NE;
    while (lo < hi) {
      int mid = (lo + hi) >> 1;
      if (pa.dst[mid] < n) lo = mid + 1; else hi = mid;
    }
    pa.offs[n] = lo;
  }
}

// ---- batched C[M,128] = A[M,128] @ B_i[128,128] for 5 weights ------------
// mode: 0 = f32 row, 1 = bf16 row,
//       2 = KV interleaved K (elem g*8+slot), 3 = KV interleaved V (+4).
struct GemmBatch {
  const __bf16* BT[5];
  void* C[5];
  const float* bias[5];  // nullptr = none
  int mode[5];
};

__global__ __launch_bounds__(256) void gemm_k128_b(const float* __restrict__ A,
                                                   GemmBatch gb, int M) {
  __shared__ __align__(16) char atile[128 * 256];
  const int y = blockIdx.y;
  const __bf16* __restrict__ BT = gb.BT[y];
  const int tid = threadIdx.x;
  const int lane = tid & 63;
  const int wave = tid >> 6;
  const int wr = wave >> 1, wc = wave & 1;
  const int row0 = blockIdx.x * 128;
  const int col0 = wc * 64;
  const int lr = lane & 15;
  const int lk = (lane >> 4) << 3;

  stage_a_tile128(A, M, row0, atile, tid);
  __syncthreads();

  f32x4 acc[4][4] = {};
#pragma unroll
  for (int kk = 0; kk < 4; ++kk) {
    const int k0 = kk * 32 + lk;
    bf16x8 a[4], b[4];
#pragma unroll
    for (int m = 0; m < 4; ++m) a[m] = read_a_frag(atile, wr * 64 + m * 16 + lr, k0);
#pragma unroll
    for (int n = 0; n < 4; ++n) b[n] = *(const bf16x8*)(BT + (size_t)(col0 + n * 16 + lr) * D + k0);
#pragma unroll
    for (int m = 0; m < 4; ++m)
#pragma unroll
      for (int n = 0; n < 4; ++n)
        acc[m][n] = MFMA(a[m], b[n], acc[m][n]);
  }
  const int rr = (lane >> 4) * 4;
  float bv[4] = {0.f, 0.f, 0.f, 0.f};
  if (gb.bias[y]) {
#pragma unroll
    for (int n = 0; n < 4; ++n) bv[n] = gb.bias[y][col0 + n * 16 + lr];
  }
  const int mode = gb.mode[y];
#pragma unroll
  for (int m = 0; m < 4; ++m)
#pragma unroll
    for (int j = 0; j < 4; ++j) {
      const int row = row0 + wr * 64 + m * 16 + rr + j;
      if (row < M) {
#pragma unroll
        for (int n = 0; n < 4; ++n) {
          const int c = col0 + n * 16 + lr;
          const float val = acc[m][n][j] + bv[n];
          if (mode == 0) {
            ((float*)gb.C[y])[(size_t)row * D + c] = val;
          } else if (mode == 1) {
            ((__bf16*)gb.C[y])[(size_t)row * D + c] = (__bf16)val;
          } else {
            // interleaved KV row: 32 groups of {k0..3, v0..3}
            const int e = ((c >> 2) << 3) + (c & 3) + (mode == 3 ? 4 : 0);
            ((__bf16*)gb.C[y])[(size_t)row * 256 + e] = (__bf16)val;
          }
        }
      }
    }
}

// ---- attn chunk pipeline macros (static reg indexing only) ---------------
// KV row interleaved: lane l32 loads ONE 16B dwordx4 = {k4|v4} per edge.
#define LD1(P, K, J, SV)                                                     \
  do {                                                                       \
    const int jj_ = (J);                                                     \
    const int jc_ = jj_ < jm ? jj_ : 0;                                      \
    int si_ = __shfl((SV), jj_ & 31, 32);                                    \
    si_ = jj_ < jm ? si_ : 0;                                                \
    kv##P[K] = *(const bf16x8*)(KV + (size_t)si_ * 256 + (l32 << 3));        \
    ee##P[K] = *(const f32x4*)(edge + (size_t)(s0 + jc_) * D + (l32 << 2));  \
  } while (0)

#define LOADC(P, C)                                                          \
  do {                                                                       \
    const int c4_ = (C) * 4;                                                 \
    const int sv_ = (c4_ < 32) ? sidx0 : sidx1;                              \
    LD1(P, 0, c4_ + 0, sv_); LD1(P, 1, c4_ + 1, sv_);                        \
    LD1(P, 2, c4_ + 2, sv_); LD1(P, 3, c4_ + 3, sv_);                        \
  } while (0)

#define CP1(P, K, J)                                                         \
  do {                                                                       \
    const int jj_ = (J);                                                     \
    f32x4 ef_ = ee##P[K];                                                    \
    float x0_ = (float)kv##P[K][0] + ef_[0];                                 \
    float x1_ = (float)kv##P[K][1] + ef_[1];                                 \
    float x2_ = (float)kv##P[K][2] + ef_[2];                                 \
    float x3_ = (float)kv##P[K][3] + ef_[3];                                 \
    float pp_ = fmaf(qs[1], x1_, qs[0] * x0_) + fmaf(qs[3], x3_, qs[2] * x2_); \
    float s_ = red32(pp_);                                                   \
    float w_ = jj_ < jm ? exp2f(s_) : 0.f;                                   \
    l += w_;                                                                 \
    a[0] = fmaf(w_, (float)kv##P[K][4] + ef_[0], a[0]);                      \
    a[1] = fmaf(w_, (float)kv##P[K][5] + ef_[1], a[1]);                      \
    a[2] = fmaf(w_, (float)kv##P[K][6] + ef_[2], a[2]);                      \
    a[3] = fmaf(w_, (float)kv##P[K][7] + ef_[3], a[3]);                      \
  } while (0)

#define COMPC(P, C)                                                          \
  do {                                                                       \
    const int cc4_ = (C) * 4;                                                \
    CP1(P, 0, cc4_ + 0); CP1(P, 1, cc4_ + 1);                                \
    CP1(P, 2, cc4_ + 2); CP1(P, 3, cc4_ + 3);                                \
  } while (0)

// ---- FUSED: R12 edge path + R7 attn path, 2:3 interleave, XCD-affine -----
// Fusion overlap (R5 vs R10 split: ~38 us): edge's MFMA/barrier phases and
// attn's gather-latency phases co-resident on each CU hide each other.
__global__ __launch_bounds__(256) __attribute__((amdgpu_waves_per_eu(3)))
void fused_edge_attn(
    const float* __restrict__ edge,
    const __bf16* __restrict__ W1bT,
    const __bf16* __restrict__ W2T,
    const __bf16* __restrict__ P1,
    const __bf16* __restrict__ P3,
    const int* __restrict__ dst,
    const int* __restrict__ src,
    const float* __restrict__ b2,
    float* __restrict__ out_fused,
    const float* __restrict__ Q,
    const __bf16* __restrict__ KV,
    const int* __restrict__ offs,
    const __bf16* __restrict__ WoT,
    const float* __restrict__ noderep,
    const float* __restrict__ gamma,
    const float* __restrict__ beta,
    float* __restrict__ out_updated) {
  __shared__ __align__(16) char atile[64 * 256];  // edge swz tile -> h1 | attn: agg + xl
  __shared__ __align__(16) char bufP3[64 * 256];  // edge: P3 gathers
  const int tid = threadIdx.x;
  // XCD-affine decode: blockIdx%8 == group%8 for all 5 roles of a group.
  const int b = blockIdx.x;
  const int x = b & 7;
  const int t = b >> 3;          // 0..1954
  const int grp = (t / 5) * 8 + x;
  const int role = t % 5;
  if (grp >= 3125) return;

  if (role >= 2) {
    // ================= EDGE path (R12: coop staging + async P3) ==========
    const int ebi = grp * 3 + (role - 2);  // 0..9374
    const int eb = ebi * 64;
    const int lane = tid & 63;
    const int wave = tid >> 6;
    const int wr = wave >> 1, wc = wave & 1;
    const int lr = lane & 15;
    const int lk = (lane >> 4) << 3;
    const int col0 = wc * 64;
    const int rr = (lane >> 4) * 4;

    // 1) async P3 gathers FIRST (0 VGPR cost, deepest in flight)
    {
      const int gr = lane >> 4;
      const int slot = lane & 15;
      int sg[4];
#pragma unroll
      for (int c = 0; c < 4; ++c) sg[c] = src[eb + wave * 16 + c * 4 + gr];
#pragma unroll
      for (int c = 0; c < 4; ++c) {
        int rl = wave * 16 + c * 4 + gr;
        int sb = (slot * 16) ^ ((rl & 7) << 4);
        gload_lds16((const char*)(P3 + (size_t)sg[c] * D) + sb,
                    bufP3 + (wave * 16 + c * 4) * 256);
      }
    }

    // 2) cooperative edge-tile staging (gemm pattern)
    stage_a_tile64(edge, NE, eb, atile, tid);
    __syncthreads();  // drains stage stores AND gather vmcnt

    // 3) MFMA1: acc = edge @ W1b
    f32x4 acc[2][4] = {};
#pragma unroll
    for (int kk = 0; kk < 4; ++kk) {
      const int k0 = kk * 32 + lk;
      bf16x8 a[2], bm[4];
#pragma unroll
      for (int m = 0; m < 2; ++m) a[m] = read_a_frag(atile, wr * 32 + m * 16 + lr, k0);
#pragma unroll
      for (int n = 0; n < 4; ++n) bm[n] = *(const bf16x8*)(W1bT + (size_t)(col0 + n * 16 + lr) * D + k0);
#pragma unroll
      for (int m = 0; m < 2; ++m)
#pragma unroll
        for (int n = 0; n < 4; ++n)
          acc[m][n] = MFMA(a[m], bm[n], acc[m][n]);
    }
    __syncthreads();  // all atile reads done before h1 overwrites

    // 4) fold: h1 = relu(acc + P1[dst] + P3g) -> atile (swizzled bf16).
    //    P1 rows sorted-dst (~6 distinct/tile, L1-hit); P3 from LDS.
#pragma unroll
    for (int m = 0; m < 2; ++m) {
#pragma unroll
      for (int j = 0; j < 4; ++j) {
        const int rl = wr * 32 + m * 16 + rr + j;
        const __bf16* __restrict__ p1r = P1 + (size_t)dst[eb + rl] * D;
#pragma unroll
        for (int n = 0; n < 4; ++n) {
          const int c = col0 + n * 16 + lr;
          int byte = (rl * 256 + c * 2) ^ ((rl & 7) << 4);
          float g3 = (float)*(const __bf16*)(bufP3 + byte);
          float v = fmaxf(acc[m][n][j] + (float)p1r[c] + g3, 0.f);
          *(__bf16*)(atile + byte) = (__bf16)v;
        }
      }
    }
    __syncthreads();

    // 5) MFMA2: fused = h1 @ W2 + b2
    float b2v[4];
#pragma unroll
    for (int n = 0; n < 4; ++n) b2v[n] = b2[col0 + n * 16 + lr];
    f32x4 acc2[2][4] = {};
#pragma unroll
    for (int kk = 0; kk < 4; ++kk) {
      const int k0 = kk * 32 + lk;
      bf16x8 a[2], bm[4];
#pragma unroll
      for (int m = 0; m < 2; ++m) a[m] = read_a_frag(atile, wr * 32 + m * 16 + lr, k0);
#pragma unroll
      for (int n = 0; n < 4; ++n) bm[n] = *(const bf16x8*)(W2T + (size_t)(col0 + n * 16 + lr) * D + k0);
#pragma unroll
      for (int m = 0; m < 2; ++m)
#pragma unroll
        for (int n = 0; n < 4; ++n)
          acc2[m][n] = MFMA(a[m], bm[n], acc2[m][n]);
    }
#pragma unroll
    for (int m = 0; m < 2; ++m)
#pragma unroll
      for (int j = 0; j < 4; ++j) {
        int rl = wr * 32 + m * 16 + rr + j;
        int e = eb + rl;
#pragma unroll
        for (int n = 0; n < 4; ++n) {
          int c = col0 + n * 16 + lr;
          out_fused[(size_t)e * D + c] = acc2[m][n][j] + b2v[n];
        }
      }
  } else {
    // ================= ATTN path (R7 chunk pipeline) =====================
    const int nw = tid >> 5;                  // node-slot 0..7 (32-lane halves)
    const int node = (grp * 2 + role) * 8 + nw;  // 6250*8 = 50000
    const int l32 = tid & 31;
    int s0 = offs[node], s1 = offs[node + 1];
    int cnt = s1 - s0;
    // Q pre-scaled by CATT in prep (folded into Wq)
    f32x4 qs = *(const f32x4*)(Q + (size_t)node * D + l32 * 4);
    float l = 0.f;
    f32x4 a = {0.f, 0.f, 0.f, 0.f};

    const int jm = cnt < 64 ? cnt : 64;
    if (jm > 0) {
      int sidx0 = 0, sidx1 = 0;
      if (l32 < cnt) sidx0 = src[s0 + l32];
      if (l32 + 32 < cnt) sidx1 = src[s0 + 32 + l32];
      bf16x8 kv0[4], kv1[4];
      f32x4 ee0[4], ee1[4];
      const int nch = (jm + 3) >> 2;
      LOADC(0, 0);
      for (int c = 0; c < nch; c += 2) {
        if (c + 1 < nch) LOADC(1, c + 1);
        COMPC(0, c);
        if (c + 2 < nch) LOADC(0, c + 2);
        if (c + 1 < nch) COMPC(1, c + 1);
      }
      for (int i = 64; i < cnt; ++i) {
        int si = src[s0 + i];
        bf16x8 kvx = *(const bf16x8*)(KV + (size_t)si * 256 + (l32 << 3));
        f32x4 ef = *(const f32x4*)(edge + (size_t)(s0 + i) * D + (l32 << 2));
        float x0 = (float)kvx[0] + ef[0], x1 = (float)kvx[1] + ef[1];
        float x2 = (float)kvx[2] + ef[2], x3 = (float)kvx[3] + ef[3];
        float pp = fmaf(qs[1], x1, qs[0] * x0) + fmaf(qs[3], x3, qs[2] * x2);
        float w = exp2f(red32(pp));
        l += w;
        a[0] = fmaf(w, (float)kvx[4] + ef[0], a[0]);
        a[1] = fmaf(w, (float)kvx[5] + ef[1], a[1]);
        a[2] = fmaf(w, (float)kvx[6] + ef[2], a[2]);
        a[3] = fmaf(w, (float)kvx[7] + ef[3], a[3]);
      }
    }
    float inv = l > 0.f ? 1.f / l : 0.f;
    f32x4 r;
    r[0] = a[0] * inv; r[1] = a[1] * inv; r[2] = a[2] * inv; r[3] = a[3] * inv;

    // ---- agg row -> swizzled bf16 LDS (row nw of a 16-row A tile) --------
    {
      bf16x4 rb;
      rb[0] = (__bf16)r[0]; rb[1] = (__bf16)r[1];
      rb[2] = (__bf16)r[2]; rb[3] = (__bf16)r[3];
      int byte = (nw * 256 + l32 * 8) ^ ((nw & 7) << 4);
      *(bf16x4*)(atile + byte) = rb;
    }
    __syncthreads();

    // ---- Wo GEMM: rows 0..7 of aggTile @ Wo; cols split 2 n-tiles/wave ---
    {
      const int wave = tid >> 6;
      const int lane = tid & 63;
      const int lr = lane & 15;
      const int lk = (lane >> 4) << 3;
      f32x4 acc[2] = {};
#pragma unroll
      for (int kk = 0; kk < 4; ++kk) {
        int k0 = kk * 32 + lk;
        bf16x8 af = read_a_frag(atile, lr, k0);
#pragma unroll
        for (int tt = 0; tt < 2; ++tt) {
          int nn = wave * 2 + tt;
          bf16x8 bm = *(const bf16x8*)(WoT + (size_t)(nn * 16 + lr) * D + k0);
          acc[tt] = MFMA(af, bm, acc[tt]);
        }
      }
      float* xl = (float*)(atile + 4096);  // [8][128]
      const int rr = (lane >> 4) * 4;
      if (rr < 8) {
#pragma unroll
        for (int tt = 0; tt < 2; ++tt) {
          int nn = wave * 2 + tt;
#pragma unroll
          for (int j = 0; j < 4; ++j)
            xl[(rr + j) * 128 + nn * 16 + lr] = acc[tt][j];
        }
      }
    }
    __syncthreads();

    // ---- LN per node-slot: updated = LN(node + aggWo) --------------------
    {
      const float* xl = (const float*)(atile + 4096);
      f32x4 xv = *(const f32x4*)(xl + nw * 128 + l32 * 4);
      f32x4 nv = *(const f32x4*)(noderep + (size_t)node * D + l32 * 4);
      float x0 = xv[0] + nv[0], x1 = xv[1] + nv[1];
      float x2 = xv[2] + nv[2], x3 = xv[3] + nv[3];
      float s = red32(x0 + x1 + x2 + x3);
      float mu = s * (1.f / 128.f);
      float d0 = x0 - mu, d1 = x1 - mu, d2 = x2 - mu, d3 = x3 - mu;
      float vv = red32(d0 * d0 + d1 * d1 + d2 * d2 + d3 * d3);
      float rstd = rsqrtf(vv * (1.f / 128.f) + 1e-5f);
      f32x4 g = *(const f32x4*)(gamma + l32 * 4);
      f32x4 bb = *(const f32x4*)(beta + l32 * 4);
      f32x4 o;
      o[0] = d0 * rstd * g[0] + bb[0];
      o[1] = d1 * rstd * g[1] + bb[1];
      o[2] = d2 * rstd * g[2] + bb[2];
      o[3] = d3 * rstd * g[3] + bb[3];
      *(f32x4*)(out_updated + (size_t)node * D + l32 * 4) = o;
    }
  }
}

// ---- launch ---------------------------------------------------------------
extern "C" void kernel_launch(void* const* d_in, const int* in_sizes, int n_in,
                              void* d_out, int out_size, void* d_ws, size_t ws_size,
                              hipStream_t stream) {
  const float* node = (const float*)d_in[0];
  const float* edge = (const float*)d_in[1];
  const int* src = (const int*)d_in[2];
  const int* dst = (const int*)d_in[3];
  const float* Wq = (const float*)d_in[4];
  const float* Wk = (const float*)d_in[5];
  const float* Wv = (const float*)d_in[6];
  const float* Wo = (const float*)d_in[7];
  const float* gamma = (const float*)d_in[8];
  const float* beta = (const float*)d_in[9];
  const float* W1 = (const float*)d_in[10];
  const float* b1 = (const float*)d_in[11];
  const float* W2 = (const float*)d_in[12];
  const float* b2 = (const float*)d_in[13];

  float* out_updated = (float*)d_out;
  float* out_fused = (float*)d_out + (size_t)NN * D;

  char* ws = (char*)d_ws;
  size_t o = 0;
  auto take = [&](size_t bytes) {
    char* p = ws + o;
    o = (o + bytes + 255) & ~(size_t)255;
    return p;
  };
  int* offs = (int*)take((NN + 1) * sizeof(int));
  __bf16* WqT = (__bf16*)take(128 * 128 * 2);
  __bf16* WkT = (__bf16*)take(128 * 128 * 2);
  __bf16* WvT = (__bf16*)take(128 * 128 * 2);
  __bf16* WoT = (__bf16*)take(128 * 128 * 2);
  __bf16* W1aT = (__bf16*)take(128 * 128 * 2);
  __bf16* W1bT = (__bf16*)take(128 * 128 * 2);
  __bf16* W1cT = (__bf16*)take(128 * 128 * 2);
  __bf16* W2T = (__bf16*)take(128 * 128 * 2);
  float* Qb = (float*)take((size_t)NN * D * 4);
  __bf16* KVb = (__bf16*)take((size_t)NN * 256 * 2);  // interleaved {k4|v4}
  __bf16* P1b = (__bf16*)take((size_t)NN * D * 2);
  __bf16* P3b = (__bf16*)take((size_t)NN * D * 2);

  PrepArgs pa;
  pa.W[0] = Wq; pa.WT[0] = WqT;
  pa.W[1] = Wk; pa.WT[1] = WkT;
  pa.W[2] = Wv; pa.WT[2] = WvT;
  pa.W[3] = Wo; pa.WT[3] = WoT;
  pa.W[4] = W1; pa.WT[4] = W1aT;
  pa.W[5] = W1 + 128 * 128; pa.WT[5] = W1bT;
  pa.W[6] = W1 + 256 * 128; pa.WT[6] = W1cT;
  pa.W[7] = W2; pa.WT[7] = W2T;
  pa.dst = dst; pa.offs = offs;
  prep_all<<<512 + (NN + 256) / 256, 256, 0, stream>>>(pa);

  int gnode = (NN + 127) / 128;
  GemmBatch gb;
  gb.BT[0] = WqT;  gb.C[0] = Qb;  gb.bias[0] = nullptr; gb.mode[0] = 0;
  gb.BT[1] = WkT;  gb.C[1] = KVb; gb.bias[1] = nullptr; gb.mode[1] = 2;
  gb.BT[2] = WvT;  gb.C[2] = KVb; gb.bias[2] = nullptr; gb.mode[2] = 3;
  gb.BT[3] = W1aT; gb.C[3] = P1b; gb.bias[3] = b1;      gb.mode[3] = 1;
  gb.BT[4] = W1cT; gb.C[4] = P3b; gb.bias[4] = nullptr; gb.mode[4] = 1;
  gemm_k128_b<<<dim3(gnode, 5), 256, 0, stream>>>(node, gb, NN);

  // fused: XCD-affine grid 8 residues x 391 slots x 5 roles (2 attn + 3 edge)
  fused_edge_attn<<<15640, 256, 0, stream>>>(edge, W1bT, W2T, P1b, P3b, dst, src,
                                             b2, out_fused, Qb, KVb, offs,
                                             WoT, node, gamma, beta, out_updated);
}